// Round 5
// baseline (422.438 us; speedup 1.0000x reference)
//
#include <hip/hip_runtime.h>
#include <math.h>

#define CC   256
#define HW   4096
#define OC3  384
#define HID  128
#define DH   32
#define NM   4
#define NPART 8
#define SCALE 0.17677669529663688f  // 32^-0.5

typedef __bf16 bf16x8 __attribute__((ext_vector_type(8)));
typedef float  f32x4  __attribute__((ext_vector_type(4)));

__device__ __forceinline__ ushort f2bf(float x) {
    union { float f; unsigned u; } v; v.f = x;
    unsigned r = v.u + 0x7fffu + ((v.u >> 16) & 1u);   // RNE
    return (ushort)(r >> 16);
}
__device__ __forceinline__ float bf2f(ushort b) {
    union { unsigned u; float f; } v; v.u = ((unsigned)b) << 16; return v.f;
}
__device__ __forceinline__ void g2l16(const void* g, void* l) {
    __builtin_amdgcn_global_load_lds(
        (const __attribute__((address_space(1))) void*)g,
        (__attribute__((address_space(3))) void*)l, 16, 0, 0);
}

// ---------------- prep: wq2t[o][c] = wqkv[o][c]*g1[c]*16 (bf16); woutt = bf16(wout)
__global__ void k_prep(const float* __restrict__ wqkv, const float* __restrict__ g1,
                       const float* __restrict__ wout,
                       ushort* __restrict__ wq2t, ushort* __restrict__ woutt) {
    int o = blockIdx.x, t = threadIdx.x;
    wq2t[(size_t)o * CC + t] = f2bf(wqkv[(size_t)o * CC + t] * g1[t] * 16.0f);
    if (o < CC && t < HID) woutt[(size_t)o * HID + t] = f2bf(wout[(size_t)o * HID + t]);
}

// ---------------- qkv MFMA GEMM, v4: raw-x input, RMS-norm in epilogue.
// v4 changes vs v3 (110us, MfmaUtil 9%, 24 barriers, xt LDS round-trip):
//  - register transpose: thread owns pixel tpix, loads its 16 c-values as
//    coalesced dwords (lanes = consecutive pixels), converts in-reg, writes
//    Bs[pix][k] directly (2 aligned b128). xt buffer + 1 barrier/step gone.
//  - 2-phase double-buffer (T3-lite): MFMA(cur) -> stage(next) -> ONE barrier
//    per K-step (8 total vs 24). g2l16/ds-writes of tile s+1 overlap MFMA(s)
//    across waves.
__global__ __launch_bounds__(256) void k_qkv(const ushort* __restrict__ wq2t,
        const float* __restrict__ x, ushort* __restrict__ qkv) {
    __shared__ __align__(16) ushort As[2][128 * 32];   // A tile [oc][32k] x2
    __shared__ __align__(16) ushort Bs[2][128 * 40];   // B tile [pix][k] x2, stride 40
    __shared__ float nrm[256];
    __shared__ float invp[128];
    int tid = threadIdx.x;
    int lin = blockIdx.x + 3 * (blockIdx.y + 32 * blockIdx.z);   // 0..3071
    int swz = (lin & 7) * 384 + (lin >> 3);                      // XCD-bijective
    int m0 = (swz % 3) * 128;
    int t_ = swz / 3;                                            // 0..1023
    int p0 = (t_ & 31) * 128;
    int b  = t_ >> 5;
    int lane = tid & 63, wid = tid >> 6;
    int l15 = tid & 15, quad = (tid >> 4) & 3;
    int wm = wid >> 1, wn = wid & 1;
    int rsub = lane >> 2, csub = (lane & 3) * 8;
    int tpix = tid & 127;           // pixel owned for B staging
    int tc8  = (tid >> 7) * 8;      // c-offset: 0 or 8 (+16 for 2nd group)
    const ushort* Ab = wq2t + (size_t)m0 * CC;
    const float*  xg = x + ((size_t)b * CC) * HW + p0 + tpix;
    float psum = 0.f;
    f32x4 acc[4][4];
    #pragma unroll
    for (int i = 0; i < 4; ++i)
        #pragma unroll
        for (int j = 0; j < 4; ++j) acc[i][j] = (f32x4){0.f, 0.f, 0.f, 0.f};

    auto stage = [&](int buf, int k0) {
        float xv[16];
        #pragma unroll
        for (int i = 0; i < 8; ++i) xv[i]     = xg[(size_t)(k0 + tc8 + i) * HW];
        #pragma unroll
        for (int i = 0; i < 8; ++i) xv[8 + i] = xg[(size_t)(k0 + tc8 + 16 + i) * HW];
        uint4 pka, pkb; ushort* oa = (ushort*)&pka; ushort* ob = (ushort*)&pkb;
        #pragma unroll
        for (int i = 0; i < 8; ++i) { float v = xv[i];     psum += v * v; oa[i] = f2bf(v); }
        #pragma unroll
        for (int i = 0; i < 8; ++i) { float v = xv[8 + i]; psum += v * v; ob[i] = f2bf(v); }
        *(uint4*)&Bs[buf][tpix * 40 + tc8]      = pka;
        *(uint4*)&Bs[buf][tpix * 40 + tc8 + 16] = pkb;
        #pragma unroll
        for (int q = 0; q < 2; ++q) {
            int rw = wid * 32 + q * 16;
            g2l16(Ab + (size_t)(rw + rsub) * CC + k0 + csub, &As[buf][rw * 32]);
        }
    };

    stage(0, 0);
    __syncthreads();
    #pragma unroll
    for (int s = 0; s < 8; ++s) {
        int cur = s & 1;
        bf16x8 af[4], bfr[4];
        #pragma unroll
        for (int mt = 0; mt < 4; ++mt)
            af[mt] = *(const bf16x8*)&As[cur][(wm * 64 + mt * 16 + l15) * 32 + quad * 8];
        #pragma unroll
        for (int nt = 0; nt < 4; ++nt)
            bfr[nt] = *(const bf16x8*)&Bs[cur][(wn * 64 + nt * 16 + l15) * 40 + quad * 8];
        #pragma unroll
        for (int mt = 0; mt < 4; ++mt)
            #pragma unroll
            for (int nt = 0; nt < 4; ++nt)
                acc[mt][nt] = __builtin_amdgcn_mfma_f32_16x16x32_bf16(
                                  af[mt], bfr[nt], acc[mt][nt], 0, 0, 0);
        if (s < 7) stage(cur ^ 1, (s + 1) * 32);
        __syncthreads();
    }
    // per-pixel inv norm: threads t and t+128 hold the two halves of sum(x^2)
    nrm[tid] = psum;
    __syncthreads();
    if (tid < 128) {
        float s = nrm[tid] + nrm[tid + 128];
        invp[tid] = 1.0f / fmaxf(sqrtf(s), 1e-12f);
    }
    __syncthreads();
    #pragma unroll
    for (int mt = 0; mt < 4; ++mt) {
        int o = m0 + wm * 64 + mt * 16 + quad * 4;
        #pragma unroll
        for (int nt = 0; nt < 4; ++nt) {
            int pixl = wn * 64 + nt * 16 + l15;
            float iv = invp[pixl];
            ushort* dst = qkv + ((size_t)(b * OC3 + o)) * HW + p0 + pixl;
            #pragma unroll
            for (int r = 0; r < 4; ++r) dst[(size_t)r * HW] = f2bf(acc[mt][nt][r] * iv);
        }
    }
}

// ---------------- k-softmax stats over bf16 k rows (uint4 loads)
__global__ void k_ksoft(const ushort* __restrict__ qkv, const float* __restrict__ memkv,
                        float* __restrict__ kmaxb, float* __restrict__ rsumb) {
    int row = blockIdx.x * 4 + (threadIdx.x >> 6);
    int lane = threadIdx.x & 63;
    int b = row >> 7, hd = row & 127;
    const ushort* kp = qkv + ((size_t)(b * OC3 + HID + hd)) * HW;
    float m = -1e30f;
    #pragma unroll
    for (int i0 = 0; i0 < HW; i0 += 512) {
        uint4 pk = *(const uint4*)&kp[i0 + lane * 8];
        const ushort* e = (const ushort*)&pk;
        #pragma unroll
        for (int j = 0; j < 8; ++j) m = fmaxf(m, bf2f(e[j]));
    }
    #pragma unroll
    for (int s = 1; s < 64; s <<= 1) m = fmaxf(m, __shfl_xor(m, s));
    const float* mk = memkv + hd * NM;
    #pragma unroll
    for (int j = 0; j < NM; ++j) m = fmaxf(m, mk[j]);
    float s = 0.f;
    #pragma unroll
    for (int i0 = 0; i0 < HW; i0 += 512) {
        uint4 pk = *(const uint4*)&kp[i0 + lane * 8];
        const ushort* e = (const ushort*)&pk;
        #pragma unroll
        for (int j = 0; j < 8; ++j) s += __expf(bf2f(e[j]) - m);
    }
    #pragma unroll
    for (int t = 1; t < 64; t <<= 1) s += __shfl_xor(s, t);
    #pragma unroll
    for (int j = 0; j < NM; ++j) s += __expf(mk[j] - m);
    if (lane == 0) { kmaxb[row] = m; rsumb[row] = 1.0f / s; }
}

// ---------------- context partials: ctxp[part][bh][d*32+e], n split 8 ways
__global__ __launch_bounds__(256) void k_ctx(const ushort* __restrict__ qkv,
        const float* __restrict__ memkv, const float* __restrict__ kmaxb,
        const float* __restrict__ rsumb, float* __restrict__ ctxp) {
    __shared__ float kl[DH][65];
    __shared__ float vl[DH][65];
    __shared__ float red[256 * 33];
    int tid = threadIdx.x;
    int bh = blockIdx.x;            // 0..127
    int part = blockIdx.y;          // 0..7
    int b = bh >> 2, h = bh & 3;
    int lr = tid >> 3;              // 0..31: k/v row this thread stages
    int nn8 = (tid & 7) * 8;        // 8-col chunk
    const ushort* kp = qkv + ((size_t)(b * OC3 + HID + h * DH) + lr) * HW + part * 512 + nn8;
    const ushort* vp = qkv + ((size_t)(b * OC3 + 2 * HID + h * DH) + lr) * HW + part * 512 + nn8;
    int rowbase = bh * DH;
    float kmr = kmaxb[rowbase + lr], rsr = rsumb[rowbase + lr];
    int slot = tid & 31, nng = tid >> 5;
    int d0 = (slot >> 2) * 4, e0 = (slot & 3) * 8;
    float acc[4][8];
    #pragma unroll
    for (int i = 0; i < 4; ++i)
        #pragma unroll
        for (int j = 0; j < 8; ++j) acc[i][j] = 0.f;
    for (int n0 = 0; n0 < 512; n0 += 64) {
        __syncthreads();
        uint4 kv4 = *(const uint4*)&kp[n0];
        uint4 vv4 = *(const uint4*)&vp[n0];
        const ushort* ke = (const ushort*)&kv4;
        const ushort* ve = (const ushort*)&vv4;
        #pragma unroll
        for (int j = 0; j < 8; ++j) {
            kl[lr][nn8 + j] = __expf(bf2f(ke[j]) - kmr) * rsr;
            vl[lr][nn8 + j] = bf2f(ve[j]);
        }
        __syncthreads();
        #pragma unroll 2
        for (int t = 0; t < 8; ++t) {
            int nn = nng * 8 + t;
            float kv[4], vv[8];
            #pragma unroll
            for (int i = 0; i < 4; ++i) kv[i] = kl[d0 + i][nn];
            #pragma unroll
            for (int j = 0; j < 8; ++j) vv[j] = vl[e0 + j][nn];
            #pragma unroll
            for (int i = 0; i < 4; ++i)
                #pragma unroll
                for (int j = 0; j < 8; ++j) acc[i][j] += kv[i] * vv[j];
        }
    }
    __syncthreads();
    #pragma unroll
    for (int i = 0; i < 4; ++i)
        #pragma unroll
        for (int j = 0; j < 8; ++j) red[tid * 33 + i * 8 + j] = acc[i][j];
    __syncthreads();
    #pragma unroll
    for (int q = 0; q < 4; ++q) {
        int o = tid * 4 + q;
        int d = o >> 5, e = o & 31;
        int sl = (d >> 2) * 4 + (e >> 3);
        int k = (d & 3) * 8 + (e & 7);
        float s = 0.f;
        #pragma unroll
        for (int g = 0; g < 8; ++g) s += red[(g * 32 + sl) * 33 + k];
        if (part == 0) {   // memory-kv contribution added once
            float km = kmaxb[rowbase + d], rsm = rsumb[rowbase + d];
            #pragma unroll
            for (int m = 0; m < NM; ++m) {
                float kw = __expf(memkv[(h * DH + d) * NM + m] - km) * rsm;
                s += kw * memkv[512 + (h * DH + e) * NM + m];
            }
        }
        ctxp[(size_t)part * 131072 + (size_t)bh * 1024 + o] = s;
    }
}

// ---------------- fold ctx into out-proj weight, once per batch:
// W2[b][oc][h*32+d] = sum_e wout[oc][h*32+e] * ctx_b[h][d][e]   (bf16)
__global__ __launch_bounds__(256) void k_w2(const float* __restrict__ ctxp,
        const ushort* __restrict__ woutt, ushort* __restrict__ W2) {
    __shared__ ushort ctxb[4 * 32 * 40];   // [h][d][e], pad 40 (80B rows, 16B-aligned)
    int tid = threadIdx.x, b = blockIdx.x;
    int wid = tid >> 6;
    int l15 = tid & 15, quad = (tid >> 4) & 3;
    // sum the 8 n-partials -> bf16 LDS (mem-kv already folded in at part 0)
    #pragma unroll
    for (int j = 0; j < 16; ++j) {
        int idx = tid + j * 256;            // 0..4095 = h*1024 + d*32 + e
        float s = 0.f;
        #pragma unroll
        for (int p = 0; p < NPART; ++p)
            s += ctxp[(size_t)p * 131072 + (size_t)b * 4096 + idx];
        int h = idx >> 10, d = (idx >> 5) & 31, e = idx & 31;
        ctxb[(h * 32 + d) * 40 + e] = f2bf(s);
    }
    __syncthreads();
    // per wave: 64 oc rows; per head: one K=32 MFMA step (M=64, N=32)
    #pragma unroll
    for (int h = 0; h < 4; ++h) {
        f32x4 acc[4][2];
        #pragma unroll
        for (int i = 0; i < 4; ++i)
            #pragma unroll
            for (int j = 0; j < 2; ++j) acc[i][j] = (f32x4){0.f, 0.f, 0.f, 0.f};
        bf16x8 af[4], bfr[2];
        #pragma unroll
        for (int mt = 0; mt < 4; ++mt)
            af[mt] = *(const bf16x8*)&woutt[(size_t)(wid * 64 + mt * 16 + l15) * HID
                                            + h * DH + quad * 8];
        #pragma unroll
        for (int nt = 0; nt < 2; ++nt)
            bfr[nt] = *(const bf16x8*)&ctxb[(h * 32 + nt * 16 + l15) * 40 + quad * 8];
        #pragma unroll
        for (int mt = 0; mt < 4; ++mt)
            #pragma unroll
            for (int nt = 0; nt < 2; ++nt)
                acc[mt][nt] = __builtin_amdgcn_mfma_f32_16x16x32_bf16(
                                  af[mt], bfr[nt], acc[mt][nt], 0, 0, 0);
        #pragma unroll
        for (int mt = 0; mt < 4; ++mt)
            #pragma unroll
            for (int nt = 0; nt < 2; ++nt)
                #pragma unroll
                for (int r = 0; r < 4; ++r) {
                    int oc = wid * 64 + mt * 16 + quad * 4 + r;
                    int d  = nt * 16 + l15;
                    W2[((size_t)b * CC + oc) * HID + h * DH + d] = f2bf(acc[mt][nt][r]);
                }
    }
}

// ---------------- final: q-softmax + single GEMM (W2_b @ softq) + bias + rms*g2
__global__ __launch_bounds__(256) void k_final(const ushort* __restrict__ qkv,
        const ushort* __restrict__ W2, const float* __restrict__ bout,
        const float* __restrict__ g2, float* __restrict__ y) {
    __shared__ __align__(16) ushort sq[64 * 136];   // [pix][hid] softmaxed q, bf16
    __shared__ __align__(16) ushort Ws[256 * 32];   // staged W2 K-tile
    __shared__ float red[64 * 17];
    __shared__ float invs[64];
    __shared__ float bl[256];
    __shared__ float gl[256];
    int tid = threadIdx.x;
    int b = blockIdx.y;
    int hwb = blockIdx.x * 64;
    int lane = tid & 63, wid = tid >> 6;
    int l15 = tid & 15, quad = (tid >> 4) & 3;
    bl[tid] = bout[tid];
    gl[tid] = g2[tid];

    // ---- softmax over d per (h=wid, pix=lane); write sq[pix][hid] bf16
    {
        const ushort* qp = qkv + ((size_t)b * OC3 + wid * DH) * HW + hwb + lane;
        float vd[32];
        float m = -1e30f;
        #pragma unroll
        for (int d = 0; d < 32; ++d) {
            float v = bf2f(qp[(size_t)d * HW]);   // 64 lanes contiguous per row
            vd[d] = v; m = fmaxf(m, v);
        }
        float s = 0.f;
        #pragma unroll
        for (int d = 0; d < 32; ++d) { float e = __expf(vd[d] - m); vd[d] = e; s += e; }
        float r_ = SCALE / s;
        #pragma unroll
        for (int q8 = 0; q8 < 4; ++q8) {
            uint4 pk; ushort* o8 = (ushort*)&pk;
            #pragma unroll
            for (int i = 0; i < 8; ++i) o8[i] = f2bf(vd[q8 * 8 + i] * r_);
            *(uint4*)&sq[lane * 136 + wid * DH + q8 * 8] = pk;
        }
    }

    // ---- GEMM: y0[256 oc][64 pix] = W2_b[256][128] @ sq^T, K=128 in 4 steps
    f32x4 acc[4][4];
    #pragma unroll
    for (int i = 0; i < 4; ++i)
        #pragma unroll
        for (int j = 0; j < 4; ++j) acc[i][j] = (f32x4){0.f, 0.f, 0.f, 0.f};
    int rsub = lane >> 2, csub = (lane & 3) * 8;
    const ushort* W2b = W2 + (size_t)b * CC * HID;
    for (int k0 = 0; k0 < HID; k0 += 32) {
        __syncthreads();    // 1st iter: also guards sq writes
        #pragma unroll
        for (int q = 0; q < 4; ++q) {
            int rw = wid * 64 + q * 16;
            g2l16(W2b + (size_t)(rw + rsub) * HID + k0 + csub, &Ws[rw * 32]);
        }
        __syncthreads();
        bf16x8 af[4], bfr[4];
        #pragma unroll
        for (int mt = 0; mt < 4; ++mt)
            af[mt] = *(const bf16x8*)&Ws[(wid * 64 + mt * 16 + l15) * 32 + quad * 8];
        #pragma unroll
        for (int nt = 0; nt < 4; ++nt)
            bfr[nt] = *(const bf16x8*)&sq[(nt * 16 + l15) * 136 + k0 + quad * 8];
        #pragma unroll
        for (int mt = 0; mt < 4; ++mt)
            #pragma unroll
            for (int nt = 0; nt < 4; ++nt)
                acc[mt][nt] = __builtin_amdgcn_mfma_f32_16x16x32_bf16(
                                  af[mt], bfr[nt], acc[mt][nt], 0, 0, 0);
    }

    // ---- epilogue: bias, rms-norm over 256 oc, *g2*16
    float part[4] = {0.f, 0.f, 0.f, 0.f};
    #pragma unroll
    for (int mt = 0; mt < 4; ++mt)
        #pragma unroll
        for (int r = 0; r < 4; ++r) {
            int oc = wid * 64 + mt * 16 + quad * 4 + r;
            float bo = bl[oc];
            #pragma unroll
            for (int nt = 0; nt < 4; ++nt) {
                float v = acc[mt][nt][r] + bo;
                acc[mt][nt][r] = v;
                part[nt] += v * v;
            }
        }
    __syncthreads();
    #pragma unroll
    for (int nt = 0; nt < 4; ++nt)
        red[(nt * 16 + l15) * 17 + wid * 4 + quad] = part[nt];
    __syncthreads();
    if (tid < 64) {
        float s = 0.f;
        #pragma unroll
        for (int g = 0; g < 16; ++g) s += red[tid * 17 + g];
        invs[tid] = 1.0f / fmaxf(sqrtf(s), 1e-12f);
    }
    __syncthreads();
    #pragma unroll
    for (int mt = 0; mt < 4; ++mt)
        #pragma unroll
        for (int nt = 0; nt < 4; ++nt) {
            int pix = nt * 16 + l15;
            float iv = invs[pix];
            #pragma unroll
            for (int r = 0; r < 4; ++r) {
                int oc = wid * 64 + mt * 16 + quad * 4 + r;
                y[((size_t)(b * CC + oc)) * HW + hwb + pix] = acc[mt][nt][r] * iv * gl[oc] * 16.0f;
            }
        }
}

extern "C" void kernel_launch(void* const* d_in, const int* in_sizes, int n_in,
                              void* d_out, int out_size, void* d_ws, size_t ws_size,
                              hipStream_t stream) {
    const float* x     = (const float*)d_in[0];
    const float* g1    = (const float*)d_in[1];
    const float* memkv = (const float*)d_in[2];
    const float* wqkv  = (const float*)d_in[3];
    const float* wout  = (const float*)d_in[4];
    const float* bout  = (const float*)d_in[5];
    const float* g2    = (const float*)d_in[6];
    float* y = (float*)d_out;

    char* w = (char*)d_ws;
    ushort* wq2t  = (ushort*)w;  w += (size_t)OC3 * CC * 2;
    ushort* woutt = (ushort*)w;  w += (size_t)CC * HID * 2;
    float*  kmaxb = (float*)w;   w += 4096 * 4;
    float*  rsumb = (float*)w;   w += 4096 * 4;
    float*  ctxp  = (float*)w;   w += (size_t)NPART * 131072 * 4;  // 4 MB
    ushort* W2    = (ushort*)w;  w += (size_t)32 * CC * HID * 2;   // 2 MB
    ushort* qkv   = (ushort*)w;  w += (size_t)32 * OC3 * HW * 2;   // 100 MB

    k_prep  <<<dim3(384),       dim3(256), 0, stream>>>(wqkv, g1, wout, wq2t, woutt);
    k_qkv   <<<dim3(3, 32, 32), dim3(256), 0, stream>>>(wq2t, x, qkv);
    k_ksoft <<<dim3(1024),      dim3(256), 0, stream>>>(qkv, memkv, kmaxb, rsumb);
    k_ctx   <<<dim3(128, 8),    dim3(256), 0, stream>>>(qkv, memkv, kmaxb, rsumb, ctxp);
    k_w2    <<<dim3(32),        dim3(256), 0, stream>>>(ctxp, woutt, W2);
    k_final <<<dim3(64, 32),    dim3(256), 0, stream>>>(qkv, W2, bout, g2, y);
}

// Round 6
// 376.380 us; speedup vs baseline: 1.1224x; 1.1224x over previous
//
#include <hip/hip_runtime.h>
#include <math.h>

#define CC   256
#define HW   4096
#define OC3  384
#define HID  128
#define DH   32
#define NM   4
#define NPART 8
#define SCALE 0.17677669529663688f  // 32^-0.5

typedef __bf16 bf16x8 __attribute__((ext_vector_type(8)));
typedef float  f32x4  __attribute__((ext_vector_type(4)));

__device__ __forceinline__ ushort f2bf(float x) {
    union { float f; unsigned u; } v; v.f = x;
    unsigned r = v.u + 0x7fffu + ((v.u >> 16) & 1u);   // RNE
    return (ushort)(r >> 16);
}
__device__ __forceinline__ float bf2f(ushort b) {
    union { unsigned u; float f; } v; v.u = ((unsigned)b) << 16; return v.f;
}
__device__ __forceinline__ void g2l16(const void* g, void* l) {
    __builtin_amdgcn_global_load_lds(
        (const __attribute__((address_space(1))) void*)g,
        (__attribute__((address_space(3))) void*)l, 16, 0, 0);
}

// ---------------- prep: wq2t[o][c] = wqkv[o][c]*g1[c]*16 (bf16); woutt = bf16(wout)
__global__ void k_prep(const float* __restrict__ wqkv, const float* __restrict__ g1,
                       const float* __restrict__ wout,
                       ushort* __restrict__ wq2t, ushort* __restrict__ woutt) {
    int o = blockIdx.x, t = threadIdx.x;
    wq2t[(size_t)o * CC + t] = f2bf(wqkv[(size_t)o * CC + t] * g1[t] * 16.0f);
    if (o < CC && t < HID) woutt[(size_t)o * HID + t] = f2bf(wout[(size_t)o * HID + t]);
}

// ---------------- qkv MFMA GEMM, v6: raw-x input, RMS-norm in epilogue.
// Fixes v4/v5's latency stall (174us, MfmaUtil 5.8%, everything idle):
//  - T14 issue-early/write-late: B-loads and A-g2l16 for tile s+1 issue at the
//    TOP of step s (dest buffers dead), MFMA(s) covers their latency; convert+
//    ds_write after MFMA; ONE barrier per step.
//  - XOR-swizzle (slot' = slot ^ ((row>>1)&3), 64B rows, no pad) on As AND Bs.
//    A-side via pre-swizzled per-lane g2l16 SOURCE (LDS dest linear, rule #21).
//    Fixes the 3.1M-conflict A-fragment read (16 rows @64B stride, one quad ->
//    2 of 8 bank groups -> 8-way; now 2-way = free).
__global__ __launch_bounds__(256) void k_qkv(const ushort* __restrict__ wq2t,
        const float* __restrict__ x, ushort* __restrict__ qkv) {
    __shared__ __align__(16) ushort As[2][128 * 32];   // [oc][32k] x2, swizzled
    __shared__ __align__(16) ushort Bs[2][128 * 32];   // [pix][32k] x2, swizzled
    __shared__ float nrm[256];
    __shared__ float invp[128];
    int tid = threadIdx.x;
    int lin = blockIdx.x + 3 * (blockIdx.y + 32 * blockIdx.z);   // 0..3071
    int swz = (lin & 7) * 384 + (lin >> 3);                      // XCD-bijective
    int m0 = (swz % 3) * 128;
    int t_ = swz / 3;                                            // 0..1023
    int p0 = (t_ & 31) * 128;
    int b  = t_ >> 5;
    int lane = tid & 63, wid = tid >> 6;
    int l15 = tid & 15, quad = (tid >> 4) & 3;
    int wm = wid >> 1, wn = wid & 1;
    int rsub = lane >> 2;
    int tpix = tid & 127;           // pixel owned for B staging
    int grp  = tid >> 7;            // 0/1: covers slots {0,2} / {1,3}
    int bsw  = (tpix >> 1) & 3;     // B swizzle key for this pixel
    const ushort* Ab = wq2t + (size_t)m0 * CC;
    const float*  xg = x + ((size_t)b * CC) * HW + p0 + tpix;
    float psum = 0.f;
    float xv[16];
    f32x4 acc[4][4];
    #pragma unroll
    for (int i = 0; i < 4; ++i)
        #pragma unroll
        for (int j = 0; j < 4; ++j) acc[i][j] = (f32x4){0.f, 0.f, 0.f, 0.f};

    auto issueB = [&](int k0) {
        #pragma unroll
        for (int i = 0; i < 8; ++i) xv[i]     = xg[(size_t)(k0 + grp * 8 + i) * HW];
        #pragma unroll
        for (int i = 0; i < 8; ++i) xv[8 + i] = xg[(size_t)(k0 + grp * 8 + 16 + i) * HW];
    };
    auto writeB = [&](int buf) {
        uint4 pka, pkb; ushort* oa = (ushort*)&pka; ushort* ob = (ushort*)&pkb;
        #pragma unroll
        for (int i = 0; i < 8; ++i) { float v = xv[i];     psum += v * v; oa[i] = f2bf(v); }
        #pragma unroll
        for (int i = 0; i < 8; ++i) { float v = xv[8 + i]; psum += v * v; ob[i] = f2bf(v); }
        *(uint4*)&Bs[buf][tpix * 32 + (( grp      ^ bsw) << 3)] = pka;
        *(uint4*)&Bs[buf][tpix * 32 + (((grp + 2) ^ bsw) << 3)] = pkb;
    };
    auto stageA = [&](int buf, int k0) {
        #pragma unroll
        for (int q = 0; q < 2; ++q) {
            int rw = wid * 32 + q * 16;
            int r  = rw + rsub;
            int slog = (lane & 3) ^ ((r >> 1) & 3);   // pre-swizzled source slot
            g2l16(Ab + (size_t)r * CC + k0 + slog * 8, &As[buf][rw * 32]);
        }
    };

    // prologue: tile 0
    issueB(0);
    stageA(0, 0);
    writeB(0);
    __syncthreads();

    #pragma unroll
    for (int s = 0; s < 8; ++s) {
        int cur = s & 1;
        if (s < 7) {          // issue next tile EARLY: latency hides under MFMA
            issueB((s + 1) * 32);
            stageA(cur ^ 1, (s + 1) * 32);
        }
        bf16x8 af[4], bfr[4];
        #pragma unroll
        for (int mt = 0; mt < 4; ++mt) {
            int ra = wm * 64 + mt * 16 + l15;
            af[mt] = *(const bf16x8*)&As[cur][ra * 32 + ((quad ^ ((ra >> 1) & 3)) << 3)];
        }
        #pragma unroll
        for (int nt = 0; nt < 4; ++nt) {
            int rb = wn * 64 + nt * 16 + l15;
            bfr[nt] = *(const bf16x8*)&Bs[cur][rb * 32 + ((quad ^ ((rb >> 1) & 3)) << 3)];
        }
        #pragma unroll
        for (int mt = 0; mt < 4; ++mt)
            #pragma unroll
            for (int nt = 0; nt < 4; ++nt)
                acc[mt][nt] = __builtin_amdgcn_mfma_f32_16x16x32_bf16(
                                  af[mt], bfr[nt], acc[mt][nt], 0, 0, 0);
        if (s < 7) writeB(cur ^ 1);     // vmcnt wait lands here, after MFMA
        __syncthreads();
    }

    // per-pixel inv norm: threads t and t+128 hold the two halves of sum(x^2)
    nrm[tid] = psum;
    __syncthreads();
    if (tid < 128) {
        float s = nrm[tid] + nrm[tid + 128];
        invp[tid] = 1.0f / fmaxf(sqrtf(s), 1e-12f);
    }
    __syncthreads();
    #pragma unroll
    for (int mt = 0; mt < 4; ++mt) {
        int o = m0 + wm * 64 + mt * 16 + quad * 4;
        #pragma unroll
        for (int nt = 0; nt < 4; ++nt) {
            int pixl = wn * 64 + nt * 16 + l15;
            float iv = invp[pixl];
            ushort* dst = qkv + ((size_t)(b * OC3 + o)) * HW + p0 + pixl;
            #pragma unroll
            for (int r = 0; r < 4; ++r) dst[(size_t)r * HW] = f2bf(acc[mt][nt][r] * iv);
        }
    }
}

// ---------------- k-softmax stats over bf16 k rows (uint4 loads)
__global__ void k_ksoft(const ushort* __restrict__ qkv, const float* __restrict__ memkv,
                        float* __restrict__ kmaxb, float* __restrict__ rsumb) {
    int row = blockIdx.x * 4 + (threadIdx.x >> 6);
    int lane = threadIdx.x & 63;
    int b = row >> 7, hd = row & 127;
    const ushort* kp = qkv + ((size_t)(b * OC3 + HID + hd)) * HW;
    float m = -1e30f;
    #pragma unroll
    for (int i0 = 0; i0 < HW; i0 += 512) {
        uint4 pk = *(const uint4*)&kp[i0 + lane * 8];
        const ushort* e = (const ushort*)&pk;
        #pragma unroll
        for (int j = 0; j < 8; ++j) m = fmaxf(m, bf2f(e[j]));
    }
    #pragma unroll
    for (int s = 1; s < 64; s <<= 1) m = fmaxf(m, __shfl_xor(m, s));
    const float* mk = memkv + hd * NM;
    #pragma unroll
    for (int j = 0; j < NM; ++j) m = fmaxf(m, mk[j]);
    float s = 0.f;
    #pragma unroll
    for (int i0 = 0; i0 < HW; i0 += 512) {
        uint4 pk = *(const uint4*)&kp[i0 + lane * 8];
        const ushort* e = (const ushort*)&pk;
        #pragma unroll
        for (int j = 0; j < 8; ++j) s += __expf(bf2f(e[j]) - m);
    }
    #pragma unroll
    for (int t = 1; t < 64; t <<= 1) s += __shfl_xor(s, t);
    #pragma unroll
    for (int j = 0; j < NM; ++j) s += __expf(mk[j] - m);
    if (lane == 0) { kmaxb[row] = m; rsumb[row] = 1.0f / s; }
}

// ---------------- context partials: ctxp[part][bh][d*32+e], n split 8 ways
__global__ __launch_bounds__(256) void k_ctx(const ushort* __restrict__ qkv,
        const float* __restrict__ memkv, const float* __restrict__ kmaxb,
        const float* __restrict__ rsumb, float* __restrict__ ctxp) {
    __shared__ float kl[DH][65];
    __shared__ float vl[DH][65];
    __shared__ float red[256 * 33];
    int tid = threadIdx.x;
    int bh = blockIdx.x;            // 0..127
    int part = blockIdx.y;          // 0..7
    int b = bh >> 2, h = bh & 3;
    int lr = tid >> 3;              // 0..31: k/v row this thread stages
    int nn8 = (tid & 7) * 8;        // 8-col chunk
    const ushort* kp = qkv + ((size_t)(b * OC3 + HID + h * DH) + lr) * HW + part * 512 + nn8;
    const ushort* vp = qkv + ((size_t)(b * OC3 + 2 * HID + h * DH) + lr) * HW + part * 512 + nn8;
    int rowbase = bh * DH;
    float kmr = kmaxb[rowbase + lr], rsr = rsumb[rowbase + lr];
    int slot = tid & 31, nng = tid >> 5;
    int d0 = (slot >> 2) * 4, e0 = (slot & 3) * 8;
    float acc[4][8];
    #pragma unroll
    for (int i = 0; i < 4; ++i)
        #pragma unroll
        for (int j = 0; j < 8; ++j) acc[i][j] = 0.f;
    for (int n0 = 0; n0 < 512; n0 += 64) {
        __syncthreads();
        uint4 kv4 = *(const uint4*)&kp[n0];
        uint4 vv4 = *(const uint4*)&vp[n0];
        const ushort* ke = (const ushort*)&kv4;
        const ushort* ve = (const ushort*)&vv4;
        #pragma unroll
        for (int j = 0; j < 8; ++j) {
            kl[lr][nn8 + j] = __expf(bf2f(ke[j]) - kmr) * rsr;
            vl[lr][nn8 + j] = bf2f(ve[j]);
        }
        __syncthreads();
        #pragma unroll 2
        for (int t = 0; t < 8; ++t) {
            int nn = nng * 8 + t;
            float kv[4], vv[8];
            #pragma unroll
            for (int i = 0; i < 4; ++i) kv[i] = kl[d0 + i][nn];
            #pragma unroll
            for (int j = 0; j < 8; ++j) vv[j] = vl[e0 + j][nn];
            #pragma unroll
            for (int i = 0; i < 4; ++i)
                #pragma unroll
                for (int j = 0; j < 8; ++j) acc[i][j] += kv[i] * vv[j];
        }
    }
    __syncthreads();
    #pragma unroll
    for (int i = 0; i < 4; ++i)
        #pragma unroll
        for (int j = 0; j < 8; ++j) red[tid * 33 + i * 8 + j] = acc[i][j];
    __syncthreads();
    #pragma unroll
    for (int q = 0; q < 4; ++q) {
        int o = tid * 4 + q;
        int d = o >> 5, e = o & 31;
        int sl = (d >> 2) * 4 + (e >> 3);
        int k = (d & 3) * 8 + (e & 7);
        float s = 0.f;
        #pragma unroll
        for (int g = 0; g < 8; ++g) s += red[(g * 32 + sl) * 33 + k];
        if (part == 0) {   // memory-kv contribution added once
            float km = kmaxb[rowbase + d], rsm = rsumb[rowbase + d];
            #pragma unroll
            for (int m = 0; m < NM; ++m) {
                float kw = __expf(memkv[(h * DH + d) * NM + m] - km) * rsm;
                s += kw * memkv[512 + (h * DH + e) * NM + m];
            }
        }
        ctxp[(size_t)part * 131072 + (size_t)bh * 1024 + o] = s;
    }
}

// ---------------- fold ctx into out-proj weight, once per batch:
// W2[b][oc][h*32+d] = sum_e wout[oc][h*32+e] * ctx_b[h][d][e]   (bf16)
__global__ __launch_bounds__(256) void k_w2(const float* __restrict__ ctxp,
        const ushort* __restrict__ woutt, ushort* __restrict__ W2) {
    __shared__ ushort ctxb[4 * 32 * 40];   // [h][d][e], pad 40 (80B rows, 16B-aligned)
    int tid = threadIdx.x, b = blockIdx.x;
    int wid = tid >> 6;
    int l15 = tid & 15, quad = (tid >> 4) & 3;
    // sum the 8 n-partials -> bf16 LDS (mem-kv already folded in at part 0)
    #pragma unroll
    for (int j = 0; j < 16; ++j) {
        int idx = tid + j * 256;            // 0..4095 = h*1024 + d*32 + e
        float s = 0.f;
        #pragma unroll
        for (int p = 0; p < NPART; ++p)
            s += ctxp[(size_t)p * 131072 + (size_t)b * 4096 + idx];
        int h = idx >> 10, d = (idx >> 5) & 31, e = idx & 31;
        ctxb[(h * 32 + d) * 40 + e] = f2bf(s);
    }
    __syncthreads();
    // per wave: 64 oc rows; per head: one K=32 MFMA step (M=64, N=32)
    #pragma unroll
    for (int h = 0; h < 4; ++h) {
        f32x4 acc[4][2];
        #pragma unroll
        for (int i = 0; i < 4; ++i)
            #pragma unroll
            for (int j = 0; j < 2; ++j) acc[i][j] = (f32x4){0.f, 0.f, 0.f, 0.f};
        bf16x8 af[4], bfr[2];
        #pragma unroll
        for (int mt = 0; mt < 4; ++mt)
            af[mt] = *(const bf16x8*)&woutt[(size_t)(wid * 64 + mt * 16 + l15) * HID
                                            + h * DH + quad * 8];
        #pragma unroll
        for (int nt = 0; nt < 2; ++nt)
            bfr[nt] = *(const bf16x8*)&ctxb[(h * 32 + nt * 16 + l15) * 40 + quad * 8];
        #pragma unroll
        for (int mt = 0; mt < 4; ++mt)
            #pragma unroll
            for (int nt = 0; nt < 2; ++nt)
                acc[mt][nt] = __builtin_amdgcn_mfma_f32_16x16x32_bf16(
                                  af[mt], bfr[nt], acc[mt][nt], 0, 0, 0);
        #pragma unroll
        for (int mt = 0; mt < 4; ++mt)
            #pragma unroll
            for (int nt = 0; nt < 2; ++nt)
                #pragma unroll
                for (int r = 0; r < 4; ++r) {
                    int oc = wid * 64 + mt * 16 + quad * 4 + r;
                    int d  = nt * 16 + l15;
                    W2[((size_t)b * CC + oc) * HID + h * DH + d] = f2bf(acc[mt][nt][r]);
                }
    }
}

// ---------------- final: q-softmax + single GEMM (W2_b @ softq) + bias + rms*g2
__global__ __launch_bounds__(256) void k_final(const ushort* __restrict__ qkv,
        const ushort* __restrict__ W2, const float* __restrict__ bout,
        const float* __restrict__ g2, float* __restrict__ y) {
    __shared__ __align__(16) ushort sq[64 * 136];   // [pix][hid] softmaxed q, bf16
    __shared__ __align__(16) ushort Ws[256 * 32];   // staged W2 K-tile
    __shared__ float red[64 * 17];
    __shared__ float invs[64];
    __shared__ float bl[256];
    __shared__ float gl[256];
    int tid = threadIdx.x;
    int b = blockIdx.y;
    int hwb = blockIdx.x * 64;
    int lane = tid & 63, wid = tid >> 6;
    int l15 = tid & 15, quad = (tid >> 4) & 3;
    bl[tid] = bout[tid];
    gl[tid] = g2[tid];

    // ---- softmax over d per (h=wid, pix=lane); write sq[pix][hid] bf16
    {
        const ushort* qp = qkv + ((size_t)b * OC3 + wid * DH) * HW + hwb + lane;
        float vd[32];
        float m = -1e30f;
        #pragma unroll
        for (int d = 0; d < 32; ++d) {
            float v = bf2f(qp[(size_t)d * HW]);   // 64 lanes contiguous per row
            vd[d] = v; m = fmaxf(m, v);
        }
        float s = 0.f;
        #pragma unroll
        for (int d = 0; d < 32; ++d) { float e = __expf(vd[d] - m); vd[d] = e; s += e; }
        float r_ = SCALE / s;
        #pragma unroll
        for (int q8 = 0; q8 < 4; ++q8) {
            uint4 pk; ushort* o8 = (ushort*)&pk;
            #pragma unroll
            for (int i = 0; i < 8; ++i) o8[i] = f2bf(vd[q8 * 8 + i] * r_);
            *(uint4*)&sq[lane * 136 + wid * DH + q8 * 8] = pk;
        }
    }

    // ---- GEMM: y0[256 oc][64 pix] = W2_b[256][128] @ sq^T, K=128 in 4 steps
    f32x4 acc[4][4];
    #pragma unroll
    for (int i = 0; i < 4; ++i)
        #pragma unroll
        for (int j = 0; j < 4; ++j) acc[i][j] = (f32x4){0.f, 0.f, 0.f, 0.f};
    int rsub = lane >> 2, csub = (lane & 3) * 8;
    const ushort* W2b = W2 + (size_t)b * CC * HID;
    for (int k0 = 0; k0 < HID; k0 += 32) {
        __syncthreads();    // 1st iter: also guards sq writes
        #pragma unroll
        for (int q = 0; q < 4; ++q) {
            int rw = wid * 64 + q * 16;
            g2l16(W2b + (size_t)(rw + rsub) * HID + k0 + csub, &Ws[rw * 32]);
        }
        __syncthreads();
        bf16x8 af[4], bfr[4];
        #pragma unroll
        for (int mt = 0; mt < 4; ++mt)
            af[mt] = *(const bf16x8*)&Ws[(wid * 64 + mt * 16 + l15) * 32 + quad * 8];
        #pragma unroll
        for (int nt = 0; nt < 4; ++nt)
            bfr[nt] = *(const bf16x8*)&sq[(nt * 16 + l15) * 136 + k0 + quad * 8];
        #pragma unroll
        for (int mt = 0; mt < 4; ++mt)
            #pragma unroll
            for (int nt = 0; nt < 4; ++nt)
                acc[mt][nt] = __builtin_amdgcn_mfma_f32_16x16x32_bf16(
                                  af[mt], bfr[nt], acc[mt][nt], 0, 0, 0);
    }

    // ---- epilogue: bias, rms-norm over 256 oc, *g2*16
    float part[4] = {0.f, 0.f, 0.f, 0.f};
    #pragma unroll
    for (int mt = 0; mt < 4; ++mt)
        #pragma unroll
        for (int r = 0; r < 4; ++r) {
            int oc = wid * 64 + mt * 16 + quad * 4 + r;
            float bo = bl[oc];
            #pragma unroll
            for (int nt = 0; nt < 4; ++nt) {
                float v = acc[mt][nt][r] + bo;
                acc[mt][nt][r] = v;
                part[nt] += v * v;
            }
        }
    __syncthreads();
    #pragma unroll
    for (int nt = 0; nt < 4; ++nt)
        red[(nt * 16 + l15) * 17 + wid * 4 + quad] = part[nt];
    __syncthreads();
    if (tid < 64) {
        float s = 0.f;
        #pragma unroll
        for (int g = 0; g < 16; ++g) s += red[tid * 17 + g];
        invs[tid] = 1.0f / fmaxf(sqrtf(s), 1e-12f);
    }
    __syncthreads();
    #pragma unroll
    for (int mt = 0; mt < 4; ++mt)
        #pragma unroll
        for (int nt = 0; nt < 4; ++nt) {
            int pix = nt * 16 + l15;
            float iv = invs[pix];
            #pragma unroll
            for (int r = 0; r < 4; ++r) {
                int oc = wid * 64 + mt * 16 + quad * 4 + r;
                y[((size_t)(b * CC + oc)) * HW + hwb + pix] = acc[mt][nt][r] * iv * gl[oc] * 16.0f;
            }
        }
}

extern "C" void kernel_launch(void* const* d_in, const int* in_sizes, int n_in,
                              void* d_out, int out_size, void* d_ws, size_t ws_size,
                              hipStream_t stream) {
    const float* x     = (const float*)d_in[0];
    const float* g1    = (const float*)d_in[1];
    const float* memkv = (const float*)d_in[2];
    const float* wqkv  = (const float*)d_in[3];
    const float* wout  = (const float*)d_in[4];
    const float* bout  = (const float*)d_in[5];
    const float* g2    = (const float*)d_in[6];
    float* y = (float*)d_out;

    char* w = (char*)d_ws;
    ushort* wq2t  = (ushort*)w;  w += (size_t)OC3 * CC * 2;
    ushort* woutt = (ushort*)w;  w += (size_t)CC * HID * 2;
    float*  kmaxb = (float*)w;   w += 4096 * 4;
    float*  rsumb = (float*)w;   w += 4096 * 4;
    float*  ctxp  = (float*)w;   w += (size_t)NPART * 131072 * 4;  // 4 MB
    ushort* W2    = (ushort*)w;  w += (size_t)32 * CC * HID * 2;   // 2 MB
    ushort* qkv   = (ushort*)w;  w += (size_t)32 * OC3 * HW * 2;   // 100 MB

    k_prep  <<<dim3(384),       dim3(256), 0, stream>>>(wqkv, g1, wout, wq2t, woutt);
    k_qkv   <<<dim3(3, 32, 32), dim3(256), 0, stream>>>(wq2t, x, qkv);
    k_ksoft <<<dim3(1024),      dim3(256), 0, stream>>>(qkv, memkv, kmaxb, rsumb);
    k_ctx   <<<dim3(128, 8),    dim3(256), 0, stream>>>(qkv, memkv, kmaxb, rsumb, ctxp);
    k_w2    <<<dim3(32),        dim3(256), 0, stream>>>(ctxp, woutt, W2);
    k_final <<<dim3(64, 32),    dim3(256), 0, stream>>>(qkv, W2, bout, g2, y);
}

// Round 7
// 376.120 us; speedup vs baseline: 1.1231x; 1.0007x over previous
//
#include <hip/hip_runtime.h>
#include <math.h>

#define CC   256
#define HW   4096
#define OC3  384
#define HID  128
#define DH   32
#define NM   4
#define NPART 8
#define SCALE 0.17677669529663688f  // 32^-0.5

typedef __bf16 bf16x8 __attribute__((ext_vector_type(8)));
typedef float  f32x4  __attribute__((ext_vector_type(4)));

__device__ __forceinline__ ushort f2bf(float x) {
    union { float f; unsigned u; } v; v.f = x;
    unsigned r = v.u + 0x7fffu + ((v.u >> 16) & 1u);   // RNE
    return (ushort)(r >> 16);
}
__device__ __forceinline__ float bf2f(ushort b) {
    union { unsigned u; float f; } v; v.u = ((unsigned)b) << 16; return v.f;
}
__device__ __forceinline__ void g2l16(const void* g, void* l) {
    __builtin_amdgcn_global_load_lds(
        (const __attribute__((address_space(1))) void*)g,
        (__attribute__((address_space(3))) void*)l, 16, 0, 0);
}

// ---------------- prep: wq2t[o][c] = wqkv[o][c]*g1[c]*16 (bf16); woutt = bf16(wout)
__global__ void k_prep(const float* __restrict__ wqkv, const float* __restrict__ g1,
                       const float* __restrict__ wout,
                       ushort* __restrict__ wq2t, ushort* __restrict__ woutt) {
    int o = blockIdx.x, t = threadIdx.x;
    wq2t[(size_t)o * CC + t] = f2bf(wqkv[(size_t)o * CC + t] * g1[t] * 16.0f);
    if (o < CC && t < HID) woutt[(size_t)o * HID + t] = f2bf(wout[(size_t)o * HID + t]);
}

// ---------------- fused rms-norm + transpose + bf16: xnT[b][pix][c]
// float4 global loads; LDS stride 36: conflict-free writes and column reads.
__global__ __launch_bounds__(256) void k_xn(const float* __restrict__ x,
                                            ushort* __restrict__ xnT) {
    __shared__ float xt[256 * 36];
    __shared__ float ps[8 * 33];
    __shared__ float invn[32];
    int tid = threadIdx.x;
    int pix0 = blockIdx.x * 32;
    int b = pix0 >> 12, hw0 = pix0 & 4095;
    int p = tid & 31, cg = tid >> 5;
    const float* xb = x + (size_t)b * CC * HW + hw0;
    {
        int cr = tid >> 3;          // 0..31: row within pass
        int chunk = tid & 7;        // 0..7: 4-pixel chunk
        #pragma unroll
        for (int pass = 0; pass < 8; ++pass) {
            int c = pass * 32 + cr;
            float4 v = *(const float4*)&xb[(size_t)c * HW + chunk * 4];
            *(float4*)&xt[c * 36 + chunk * 4] = v;
        }
    }
    __syncthreads();
    float s = 0.f;
    #pragma unroll 8
    for (int i = 0; i < 32; ++i) { float v = xt[(cg * 32 + i) * 36 + p]; s += v * v; }
    ps[cg * 33 + p] = s;
    __syncthreads();
    if (tid < 32) {
        float t = 0.f;
        #pragma unroll
        for (int g = 0; g < 8; ++g) t += ps[g * 33 + tid];
        invn[tid] = 1.0f / fmaxf(sqrtf(t), 1e-12f);
    }
    __syncthreads();
    float inv = invn[p];
    ushort* dst = xnT + ((size_t)(pix0 + p)) * CC + cg * 32;
    #pragma unroll
    for (int q = 0; q < 4; ++q) {
        uint4 pk; ushort* o8 = (ushort*)&pk;
        #pragma unroll
        for (int i = 0; i < 8; ++i) o8[i] = f2bf(xt[(cg * 32 + q * 8 + i) * 36 + p] * inv);
        *(uint4*)&dst[q * 8] = pk;
    }
}

// ---------------- qkv MFMA GEMM, v7: bf16 xnT input (R3 split revert), plus:
//  - g2l16 BOTH operands (2+2 chunks/thread/step, no VGPR round-trip/convert)
//  - XOR chunk swizzle (chunk' = chunk ^ ((row>>1)&3)) on As AND Bs via
//    pre-swizzled g2l16 SOURCE (LDS dest linear, rule #21). Kills the 3.1M
//    A/B-fragment 8-way bank conflicts R3's version ran with (verified 0 in R6).
//  - 1 barrier/step 2-phase: stage(next) -> frags(cur) -> MFMA -> barrier.
//    (compiler's pre-barrier vmcnt(0) drains the g2l16; MFMA+other waves
//    cover the latency.)
__global__ __launch_bounds__(256) void k_qkv(const ushort* __restrict__ wq2t,
        const ushort* __restrict__ xnT, ushort* __restrict__ qkv) {
    __shared__ __align__(16) ushort As[2][128 * 32];   // [oc][32k] x2, chunk-swizzled
    __shared__ __align__(16) ushort Bs[2][128 * 32];   // [pix][32k] x2, chunk-swizzled
    int tid = threadIdx.x;
    int lin = blockIdx.x + 3 * (blockIdx.y + 32 * blockIdx.z);   // 0..3071
    int swz = (lin & 7) * 384 + (lin >> 3);                      // XCD-bijective
    int m0 = (swz % 3) * 128;
    int t_ = swz / 3;                                            // 0..1023
    int p0 = (t_ & 31) * 128;
    int b  = t_ >> 5;
    int lane = tid & 63, wid = tid >> 6;
    int l15 = tid & 15, quad = (tid >> 4) & 3;
    int wm = wid >> 1, wn = wid & 1;
    int rsub = lane >> 2;
    const ushort* Ab = wq2t + (size_t)m0 * CC;
    const ushort* Bb = xnT + ((size_t)(b * HW + p0)) * CC;
    f32x4 acc[4][4];
    #pragma unroll
    for (int i = 0; i < 4; ++i)
        #pragma unroll
        for (int j = 0; j < 4; ++j) acc[i][j] = (f32x4){0.f, 0.f, 0.f, 0.f};

    auto stage = [&](int buf, int k0) {
        #pragma unroll
        for (int q = 0; q < 2; ++q) {
            int rw = wid * 32 + q * 16;
            int r  = rw + rsub;
            int sc = (lane & 3) ^ ((r >> 1) & 3);   // pre-swizzled source chunk
            g2l16(Ab + (size_t)r * CC + k0 + sc * 8, &As[buf][rw * 32]);
            g2l16(Bb + (size_t)r * CC + k0 + sc * 8, &Bs[buf][rw * 32]);
        }
    };

    stage(0, 0);
    __syncthreads();
    #pragma unroll
    for (int s = 0; s < 8; ++s) {
        int cur = s & 1;
        if (s < 7) stage(cur ^ 1, (s + 1) * 32);   // issue early, drain at barrier
        bf16x8 af[4], bfr[4];
        #pragma unroll
        for (int mt = 0; mt < 4; ++mt) {
            int ra = wm * 64 + mt * 16 + l15;
            af[mt] = *(const bf16x8*)&As[cur][ra * 32 + ((quad ^ ((ra >> 1) & 3)) << 3)];
        }
        #pragma unroll
        for (int nt = 0; nt < 4; ++nt) {
            int rb = wn * 64 + nt * 16 + l15;
            bfr[nt] = *(const bf16x8*)&Bs[cur][rb * 32 + ((quad ^ ((rb >> 1) & 3)) << 3)];
        }
        #pragma unroll
        for (int mt = 0; mt < 4; ++mt)
            #pragma unroll
            for (int nt = 0; nt < 4; ++nt)
                acc[mt][nt] = __builtin_amdgcn_mfma_f32_16x16x32_bf16(
                                  af[mt], bfr[nt], acc[mt][nt], 0, 0, 0);
        __syncthreads();
    }
    #pragma unroll
    for (int mt = 0; mt < 4; ++mt) {
        int o = m0 + wm * 64 + mt * 16 + quad * 4;
        #pragma unroll
        for (int nt = 0; nt < 4; ++nt) {
            int pix = p0 + wn * 64 + nt * 16 + l15;
            ushort* dst = qkv + ((size_t)(b * OC3 + o)) * HW + pix;
            #pragma unroll
            for (int r = 0; r < 4; ++r) dst[(size_t)r * HW] = f2bf(acc[mt][nt][r]);
        }
    }
}

// ---------------- k-softmax stats over bf16 k rows (uint4 loads)
__global__ void k_ksoft(const ushort* __restrict__ qkv, const float* __restrict__ memkv,
                        float* __restrict__ kmaxb, float* __restrict__ rsumb) {
    int row = blockIdx.x * 4 + (threadIdx.x >> 6);
    int lane = threadIdx.x & 63;
    int b = row >> 7, hd = row & 127;
    const ushort* kp = qkv + ((size_t)(b * OC3 + HID + hd)) * HW;
    float m = -1e30f;
    #pragma unroll
    for (int i0 = 0; i0 < HW; i0 += 512) {
        uint4 pk = *(const uint4*)&kp[i0 + lane * 8];
        const ushort* e = (const ushort*)&pk;
        #pragma unroll
        for (int j = 0; j < 8; ++j) m = fmaxf(m, bf2f(e[j]));
    }
    #pragma unroll
    for (int s = 1; s < 64; s <<= 1) m = fmaxf(m, __shfl_xor(m, s));
    const float* mk = memkv + hd * NM;
    #pragma unroll
    for (int j = 0; j < NM; ++j) m = fmaxf(m, mk[j]);
    float s = 0.f;
    #pragma unroll
    for (int i0 = 0; i0 < HW; i0 += 512) {
        uint4 pk = *(const uint4*)&kp[i0 + lane * 8];
        const ushort* e = (const ushort*)&pk;
        #pragma unroll
        for (int j = 0; j < 8; ++j) s += __expf(bf2f(e[j]) - m);
    }
    #pragma unroll
    for (int t = 1; t < 64; t <<= 1) s += __shfl_xor(s, t);
    #pragma unroll
    for (int j = 0; j < NM; ++j) s += __expf(mk[j] - m);
    if (lane == 0) { kmaxb[row] = m; rsumb[row] = 1.0f / s; }
}

// ---------------- context partials: ctxp[part][bh][d*32+e], n split 8 ways
__global__ __launch_bounds__(256) void k_ctx(const ushort* __restrict__ qkv,
        const float* __restrict__ memkv, const float* __restrict__ kmaxb,
        const float* __restrict__ rsumb, float* __restrict__ ctxp) {
    __shared__ float kl[DH][65];
    __shared__ float vl[DH][65];
    __shared__ float red[256 * 33];
    int tid = threadIdx.x;
    int bh = blockIdx.x;            // 0..127
    int part = blockIdx.y;          // 0..7
    int b = bh >> 2, h = bh & 3;
    int lr = tid >> 3;              // 0..31: k/v row this thread stages
    int nn8 = (tid & 7) * 8;        // 8-col chunk
    const ushort* kp = qkv + ((size_t)(b * OC3 + HID + h * DH) + lr) * HW + part * 512 + nn8;
    const ushort* vp = qkv + ((size_t)(b * OC3 + 2 * HID + h * DH) + lr) * HW + part * 512 + nn8;
    int rowbase = bh * DH;
    float kmr = kmaxb[rowbase + lr], rsr = rsumb[rowbase + lr];
    int slot = tid & 31, nng = tid >> 5;
    int d0 = (slot >> 2) * 4, e0 = (slot & 3) * 8;
    float acc[4][8];
    #pragma unroll
    for (int i = 0; i < 4; ++i)
        #pragma unroll
        for (int j = 0; j < 8; ++j) acc[i][j] = 0.f;
    for (int n0 = 0; n0 < 512; n0 += 64) {
        __syncthreads();
        uint4 kv4 = *(const uint4*)&kp[n0];
        uint4 vv4 = *(const uint4*)&vp[n0];
        const ushort* ke = (const ushort*)&kv4;
        const ushort* ve = (const ushort*)&vv4;
        #pragma unroll
        for (int j = 0; j < 8; ++j) {
            kl[lr][nn8 + j] = __expf(bf2f(ke[j]) - kmr) * rsr;
            vl[lr][nn8 + j] = bf2f(ve[j]);
        }
        __syncthreads();
        #pragma unroll 2
        for (int t = 0; t < 8; ++t) {
            int nn = nng * 8 + t;
            float kv[4], vv[8];
            #pragma unroll
            for (int i = 0; i < 4; ++i) kv[i] = kl[d0 + i][nn];
            #pragma unroll
            for (int j = 0; j < 8; ++j) vv[j] = vl[e0 + j][nn];
            #pragma unroll
            for (int i = 0; i < 4; ++i)
                #pragma unroll
                for (int j = 0; j < 8; ++j) acc[i][j] += kv[i] * vv[j];
        }
    }
    __syncthreads();
    #pragma unroll
    for (int i = 0; i < 4; ++i)
        #pragma unroll
        for (int j = 0; j < 8; ++j) red[tid * 33 + i * 8 + j] = acc[i][j];
    __syncthreads();
    #pragma unroll
    for (int q = 0; q < 4; ++q) {
        int o = tid * 4 + q;
        int d = o >> 5, e = o & 31;
        int sl = (d >> 2) * 4 + (e >> 3);
        int k = (d & 3) * 8 + (e & 7);
        float s = 0.f;
        #pragma unroll
        for (int g = 0; g < 8; ++g) s += red[(g * 32 + sl) * 33 + k];
        if (part == 0) {   // memory-kv contribution added once
            float km = kmaxb[rowbase + d], rsm = rsumb[rowbase + d];
            #pragma unroll
            for (int m = 0; m < NM; ++m) {
                float kw = __expf(memkv[(h * DH + d) * NM + m] - km) * rsm;
                s += kw * memkv[512 + (h * DH + e) * NM + m];
            }
        }
        ctxp[(size_t)part * 131072 + (size_t)bh * 1024 + o] = s;
    }
}

// ---------------- fold ctx into out-proj weight, once per batch:
// W2[b][oc][h*32+d] = sum_e wout[oc][h*32+e] * ctx_b[h][d][e]   (bf16)
__global__ __launch_bounds__(256) void k_w2(const float* __restrict__ ctxp,
        const ushort* __restrict__ woutt, ushort* __restrict__ W2) {
    __shared__ ushort ctxb[4 * 32 * 40];   // [h][d][e], pad 40 (80B rows, 16B-aligned)
    int tid = threadIdx.x, b = blockIdx.x;
    int wid = tid >> 6;
    int l15 = tid & 15, quad = (tid >> 4) & 3;
    // sum the 8 n-partials -> bf16 LDS (mem-kv already folded in at part 0)
    #pragma unroll
    for (int j = 0; j < 16; ++j) {
        int idx = tid + j * 256;            // 0..4095 = h*1024 + d*32 + e
        float s = 0.f;
        #pragma unroll
        for (int p = 0; p < NPART; ++p)
            s += ctxp[(size_t)p * 131072 + (size_t)b * 4096 + idx];
        int h = idx >> 10, d = (idx >> 5) & 31, e = idx & 31;
        ctxb[(h * 32 + d) * 40 + e] = f2bf(s);
    }
    __syncthreads();
    // per wave: 64 oc rows; per head: one K=32 MFMA step (M=64, N=32)
    #pragma unroll
    for (int h = 0; h < 4; ++h) {
        f32x4 acc[4][2];
        #pragma unroll
        for (int i = 0; i < 4; ++i)
            #pragma unroll
            for (int j = 0; j < 2; ++j) acc[i][j] = (f32x4){0.f, 0.f, 0.f, 0.f};
        bf16x8 af[4], bfr[2];
        #pragma unroll
        for (int mt = 0; mt < 4; ++mt)
            af[mt] = *(const bf16x8*)&woutt[(size_t)(wid * 64 + mt * 16 + l15) * HID
                                            + h * DH + quad * 8];
        #pragma unroll
        for (int nt = 0; nt < 2; ++nt)
            bfr[nt] = *(const bf16x8*)&ctxb[(h * 32 + nt * 16 + l15) * 40 + quad * 8];
        #pragma unroll
        for (int mt = 0; mt < 4; ++mt)
            #pragma unroll
            for (int nt = 0; nt < 2; ++nt)
                acc[mt][nt] = __builtin_amdgcn_mfma_f32_16x16x32_bf16(
                                  af[mt], bfr[nt], acc[mt][nt], 0, 0, 0);
        #pragma unroll
        for (int mt = 0; mt < 4; ++mt)
            #pragma unroll
            for (int nt = 0; nt < 2; ++nt)
                #pragma unroll
                for (int r = 0; r < 4; ++r) {
                    int oc = wid * 64 + mt * 16 + quad * 4 + r;
                    int d  = nt * 16 + l15;
                    W2[((size_t)b * CC + oc) * HID + h * DH + d] = f2bf(acc[mt][nt][r]);
                }
    }
}

// ---------------- final: q-softmax + single GEMM (W2_b @ softq) + bias + rms*g2
__global__ __launch_bounds__(256) void k_final(const ushort* __restrict__ qkv,
        const ushort* __restrict__ W2, const float* __restrict__ bout,
        const float* __restrict__ g2, float* __restrict__ y) {
    __shared__ __align__(16) ushort sq[64 * 136];   // [pix][hid] softmaxed q, bf16
    __shared__ __align__(16) ushort Ws[256 * 32];   // staged W2 K-tile
    __shared__ float red[64 * 17];
    __shared__ float invs[64];
    __shared__ float bl[256];
    __shared__ float gl[256];
    int tid = threadIdx.x;
    int b = blockIdx.y;
    int hwb = blockIdx.x * 64;
    int lane = tid & 63, wid = tid >> 6;
    int l15 = tid & 15, quad = (tid >> 4) & 3;
    bl[tid] = bout[tid];
    gl[tid] = g2[tid];

    // ---- softmax over d per (h=wid, pix=lane); write sq[pix][hid] bf16
    {
        const ushort* qp = qkv + ((size_t)b * OC3 + wid * DH) * HW + hwb + lane;
        float vd[32];
        float m = -1e30f;
        #pragma unroll
        for (int d = 0; d < 32; ++d) {
            float v = bf2f(qp[(size_t)d * HW]);   // 64 lanes contiguous per row
            vd[d] = v; m = fmaxf(m, v);
        }
        float s = 0.f;
        #pragma unroll
        for (int d = 0; d < 32; ++d) { float e = __expf(vd[d] - m); vd[d] = e; s += e; }
        float r_ = SCALE / s;
        #pragma unroll
        for (int q8 = 0; q8 < 4; ++q8) {
            uint4 pk; ushort* o8 = (ushort*)&pk;
            #pragma unroll
            for (int i = 0; i < 8; ++i) o8[i] = f2bf(vd[q8 * 8 + i] * r_);
            *(uint4*)&sq[lane * 136 + wid * DH + q8 * 8] = pk;
        }
    }

    // ---- GEMM: y0[256 oc][64 pix] = W2_b[256][128] @ sq^T, K=128 in 4 steps
    f32x4 acc[4][4];
    #pragma unroll
    for (int i = 0; i < 4; ++i)
        #pragma unroll
        for (int j = 0; j < 4; ++j) acc[i][j] = (f32x4){0.f, 0.f, 0.f, 0.f};
    int rsub = lane >> 2, csub = (lane & 3) * 8;
    const ushort* W2b = W2 + (size_t)b * CC * HID;
    for (int k0 = 0; k0 < HID; k0 += 32) {
        __syncthreads();    // 1st iter: also guards sq writes
        #pragma unroll
        for (int q = 0; q < 4; ++q) {
            int rw = wid * 64 + q * 16;
            g2l16(W2b + (size_t)(rw + rsub) * HID + k0 + csub, &Ws[rw * 32]);
        }
        __syncthreads();
        bf16x8 af[4], bfr[4];
        #pragma unroll
        for (int mt = 0; mt < 4; ++mt)
            af[mt] = *(const bf16x8*)&Ws[(wid * 64 + mt * 16 + l15) * 32 + quad * 8];
        #pragma unroll
        for (int nt = 0; nt < 4; ++nt)
            bfr[nt] = *(const bf16x8*)&sq[(nt * 16 + l15) * 136 + k0 + quad * 8];
        #pragma unroll
        for (int mt = 0; mt < 4; ++mt)
            #pragma unroll
            for (int nt = 0; nt < 4; ++nt)
                acc[mt][nt] = __builtin_amdgcn_mfma_f32_16x16x32_bf16(
                                  af[mt], bfr[nt], acc[mt][nt], 0, 0, 0);
    }

    // ---- epilogue: bias, rms-norm over 256 oc, *g2*16
    float part[4] = {0.f, 0.f, 0.f, 0.f};
    #pragma unroll
    for (int mt = 0; mt < 4; ++mt)
        #pragma unroll
        for (int r = 0; r < 4; ++r) {
            int oc = wid * 64 + mt * 16 + quad * 4 + r;
            float bo = bl[oc];
            #pragma unroll
            for (int nt = 0; nt < 4; ++nt) {
                float v = acc[mt][nt][r] + bo;
                acc[mt][nt][r] = v;
                part[nt] += v * v;
            }
        }
    __syncthreads();
    #pragma unroll
    for (int nt = 0; nt < 4; ++nt)
        red[(nt * 16 + l15) * 17 + wid * 4 + quad] = part[nt];
    __syncthreads();
    if (tid < 64) {
        float s = 0.f;
        #pragma unroll
        for (int g = 0; g < 16; ++g) s += red[tid * 17 + g];
        invs[tid] = 1.0f / fmaxf(sqrtf(s), 1e-12f);
    }
    __syncthreads();
    #pragma unroll
    for (int mt = 0; mt < 4; ++mt)
        #pragma unroll
        for (int nt = 0; nt < 4; ++nt) {
            int pix = nt * 16 + l15;
            float iv = invs[pix];
            #pragma unroll
            for (int r = 0; r < 4; ++r) {
                int oc = wid * 64 + mt * 16 + quad * 4 + r;
                y[((size_t)(b * CC + oc)) * HW + hwb + pix] = acc[mt][nt][r] * iv * gl[oc] * 16.0f;
            }
        }
}

extern "C" void kernel_launch(void* const* d_in, const int* in_sizes, int n_in,
                              void* d_out, int out_size, void* d_ws, size_t ws_size,
                              hipStream_t stream) {
    const float* x     = (const float*)d_in[0];
    const float* g1    = (const float*)d_in[1];
    const float* memkv = (const float*)d_in[2];
    const float* wqkv  = (const float*)d_in[3];
    const float* wout  = (const float*)d_in[4];
    const float* bout  = (const float*)d_in[5];
    const float* g2    = (const float*)d_in[6];
    float* y = (float*)d_out;

    char* w = (char*)d_ws;
    ushort* wq2t  = (ushort*)w;  w += (size_t)OC3 * CC * 2;
    ushort* woutt = (ushort*)w;  w += (size_t)CC * HID * 2;
    float*  kmaxb = (float*)w;   w += 4096 * 4;
    float*  rsumb = (float*)w;   w += 4096 * 4;
    float*  ctxp  = (float*)w;   w += (size_t)NPART * 131072 * 4;  // 4 MB
    ushort* W2    = (ushort*)w;  w += (size_t)32 * CC * HID * 2;   // 2 MB
    ushort* xnT   = (ushort*)w;  w += (size_t)32 * HW * CC * 2;    // 67 MB
    ushort* qkv   = (ushort*)w;  w += (size_t)32 * OC3 * HW * 2;   // 100 MB

    k_prep  <<<dim3(384),       dim3(256), 0, stream>>>(wqkv, g1, wout, wq2t, woutt);
    k_xn    <<<dim3(4096),      dim3(256), 0, stream>>>(x, xnT);
    k_qkv   <<<dim3(3, 32, 32), dim3(256), 0, stream>>>(wq2t, xnT, qkv);
    k_ksoft <<<dim3(1024),      dim3(256), 0, stream>>>(qkv, memkv, kmaxb, rsumb);
    k_ctx   <<<dim3(128, 8),    dim3(256), 0, stream>>>(qkv, memkv, kmaxb, rsumb, ctxp);
    k_w2    <<<dim3(32),        dim3(256), 0, stream>>>(ctxp, woutt, W2);
    k_final <<<dim3(64, 32),    dim3(256), 0, stream>>>(qkv, W2, bout, g2, y);
}

// Round 8
// 366.076 us; speedup vs baseline: 1.1540x; 1.0274x over previous
//
#include <hip/hip_runtime.h>
#include <math.h>

#define CC   256
#define HW   4096
#define OC3  384
#define HID  128
#define DH   32
#define NM   4
#define NPART 8
#define SCALE 0.17677669529663688f  // 32^-0.5

typedef __bf16 bf16x8 __attribute__((ext_vector_type(8)));
typedef float  f32x4  __attribute__((ext_vector_type(4)));

__device__ __forceinline__ ushort f2bf(float x) {
    union { float f; unsigned u; } v; v.f = x;
    unsigned r = v.u + 0x7fffu + ((v.u >> 16) & 1u);   // RNE
    return (ushort)(r >> 16);
}
__device__ __forceinline__ float bf2f(ushort b) {
    union { unsigned u; float f; } v; v.u = ((unsigned)b) << 16; return v.f;
}
__device__ __forceinline__ void g2l16(const void* g, void* l) {
    __builtin_amdgcn_global_load_lds(
        (const __attribute__((address_space(1))) void*)g,
        (__attribute__((address_space(3))) void*)l, 16, 0, 0);
}

// ---------------- fused rms-norm + transpose + bf16: xnT[b][pix][c]
// float4 global loads; LDS stride 36: conflict-free writes and column reads.
// k_prep merged in: blocks 0..383 also build wq2t/woutt (saves a launch).
__global__ __launch_bounds__(256) void k_xn(const float* __restrict__ x,
        const float* __restrict__ wqkv, const float* __restrict__ g1,
        const float* __restrict__ wout,
        ushort* __restrict__ wq2t, ushort* __restrict__ woutt,
        ushort* __restrict__ xnT) {
    __shared__ float xt[256 * 36];
    __shared__ float ps[8 * 33];
    __shared__ float invn[32];
    int tid = threadIdx.x;
    if (blockIdx.x < 384) {           // merged k_prep
        int o = blockIdx.x;
        wq2t[(size_t)o * CC + tid] = f2bf(wqkv[(size_t)o * CC + tid] * g1[tid] * 16.0f);
        if (o < CC && tid < HID) woutt[(size_t)o * HID + tid] = f2bf(wout[(size_t)o * HID + tid]);
    }
    int pix0 = blockIdx.x * 32;
    int b = pix0 >> 12, hw0 = pix0 & 4095;
    int p = tid & 31, cg = tid >> 5;
    const float* xb = x + (size_t)b * CC * HW + hw0;
    {
        int cr = tid >> 3;          // 0..31: row within pass
        int chunk = tid & 7;        // 0..7: 4-pixel chunk
        #pragma unroll
        for (int pass = 0; pass < 8; ++pass) {
            int c = pass * 32 + cr;
            float4 v = *(const float4*)&xb[(size_t)c * HW + chunk * 4];
            *(float4*)&xt[c * 36 + chunk * 4] = v;
        }
    }
    __syncthreads();
    float s = 0.f;
    #pragma unroll 8
    for (int i = 0; i < 32; ++i) { float v = xt[(cg * 32 + i) * 36 + p]; s += v * v; }
    ps[cg * 33 + p] = s;
    __syncthreads();
    if (tid < 32) {
        float t = 0.f;
        #pragma unroll
        for (int g = 0; g < 8; ++g) t += ps[g * 33 + tid];
        invn[tid] = 1.0f / fmaxf(sqrtf(t), 1e-12f);
    }
    __syncthreads();
    float inv = invn[p];
    ushort* dst = xnT + ((size_t)(pix0 + p)) * CC + cg * 32;
    #pragma unroll
    for (int q = 0; q < 4; ++q) {
        uint4 pk; ushort* o8 = (ushort*)&pk;
        #pragma unroll
        for (int i = 0; i < 8; ++i) o8[i] = f2bf(xt[(cg * 32 + q * 8 + i) * 36 + p] * inv);
        *(uint4*)&dst[q * 8] = pk;
    }
}

// ---------------- qkv MFMA GEMM (R7 structure: g2l16 both operands,
// source-side XOR swizzle verified 0-conflict, 1 barrier/step)
__global__ __launch_bounds__(256) void k_qkv(const ushort* __restrict__ wq2t,
        const ushort* __restrict__ xnT, ushort* __restrict__ qkv) {
    __shared__ __align__(16) ushort As[2][128 * 32];
    __shared__ __align__(16) ushort Bs[2][128 * 32];
    int tid = threadIdx.x;
    int lin = blockIdx.x + 3 * (blockIdx.y + 32 * blockIdx.z);   // 0..3071
    int swz = (lin & 7) * 384 + (lin >> 3);                      // XCD-bijective
    int m0 = (swz % 3) * 128;
    int t_ = swz / 3;                                            // 0..1023
    int p0 = (t_ & 31) * 128;
    int b  = t_ >> 5;
    int lane = tid & 63, wid = tid >> 6;
    int l15 = tid & 15, quad = (tid >> 4) & 3;
    int wm = wid >> 1, wn = wid & 1;
    int rsub = lane >> 2;
    const ushort* Ab = wq2t + (size_t)m0 * CC;
    const ushort* Bb = xnT + ((size_t)(b * HW + p0)) * CC;
    f32x4 acc[4][4];
    #pragma unroll
    for (int i = 0; i < 4; ++i)
        #pragma unroll
        for (int j = 0; j < 4; ++j) acc[i][j] = (f32x4){0.f, 0.f, 0.f, 0.f};

    auto stage = [&](int buf, int k0) {
        #pragma unroll
        for (int q = 0; q < 2; ++q) {
            int rw = wid * 32 + q * 16;
            int r  = rw + rsub;
            int sc = (lane & 3) ^ ((r >> 1) & 3);   // pre-swizzled source chunk
            g2l16(Ab + (size_t)r * CC + k0 + sc * 8, &As[buf][rw * 32]);
            g2l16(Bb + (size_t)r * CC + k0 + sc * 8, &Bs[buf][rw * 32]);
        }
    };

    stage(0, 0);
    __syncthreads();
    #pragma unroll
    for (int s = 0; s < 8; ++s) {
        int cur = s & 1;
        if (s < 7) stage(cur ^ 1, (s + 1) * 32);
        bf16x8 af[4], bfr[4];
        #pragma unroll
        for (int mt = 0; mt < 4; ++mt) {
            int ra = wm * 64 + mt * 16 + l15;
            af[mt] = *(const bf16x8*)&As[cur][ra * 32 + ((quad ^ ((ra >> 1) & 3)) << 3)];
        }
        #pragma unroll
        for (int nt = 0; nt < 4; ++nt) {
            int rb = wn * 64 + nt * 16 + l15;
            bfr[nt] = *(const bf16x8*)&Bs[cur][rb * 32 + ((quad ^ ((rb >> 1) & 3)) << 3)];
        }
        #pragma unroll
        for (int mt = 0; mt < 4; ++mt)
            #pragma unroll
            for (int nt = 0; nt < 4; ++nt)
                acc[mt][nt] = __builtin_amdgcn_mfma_f32_16x16x32_bf16(
                                  af[mt], bfr[nt], acc[mt][nt], 0, 0, 0);
        __syncthreads();
    }
    #pragma unroll
    for (int mt = 0; mt < 4; ++mt) {
        int o = m0 + wm * 64 + mt * 16 + quad * 4;
        #pragma unroll
        for (int nt = 0; nt < 4; ++nt) {
            int pix = p0 + wn * 64 + nt * 16 + l15;
            ushort* dst = qkv + ((size_t)(b * OC3 + o)) * HW + pix;
            #pragma unroll
            for (int r = 0; r < 4; ++r) dst[(size_t)r * HW] = f2bf(acc[mt][nt][r]);
        }
    }
}

// ---------------- k-softmax stats over bf16 k rows (uint4 loads)
__global__ void k_ksoft(const ushort* __restrict__ qkv, const float* __restrict__ memkv,
                        float* __restrict__ kmaxb, float* __restrict__ rsumb) {
    int row = blockIdx.x * 4 + (threadIdx.x >> 6);
    int lane = threadIdx.x & 63;
    int b = row >> 7, hd = row & 127;
    const ushort* kp = qkv + ((size_t)(b * OC3 + HID + hd)) * HW;
    float m = -1e30f;
    #pragma unroll
    for (int i0 = 0; i0 < HW; i0 += 512) {
        uint4 pk = *(const uint4*)&kp[i0 + lane * 8];
        const ushort* e = (const ushort*)&pk;
        #pragma unroll
        for (int j = 0; j < 8; ++j) m = fmaxf(m, bf2f(e[j]));
    }
    #pragma unroll
    for (int s = 1; s < 64; s <<= 1) m = fmaxf(m, __shfl_xor(m, s));
    const float* mk = memkv + hd * NM;
    #pragma unroll
    for (int j = 0; j < NM; ++j) m = fmaxf(m, mk[j]);
    float s = 0.f;
    #pragma unroll
    for (int i0 = 0; i0 < HW; i0 += 512) {
        uint4 pk = *(const uint4*)&kp[i0 + lane * 8];
        const ushort* e = (const ushort*)&pk;
        #pragma unroll
        for (int j = 0; j < 8; ++j) s += __expf(bf2f(e[j]) - m);
    }
    #pragma unroll
    for (int t = 1; t < 64; t <<= 1) s += __shfl_xor(s, t);
    #pragma unroll
    for (int j = 0; j < NM; ++j) s += __expf(mk[j] - m);
    if (lane == 0) { kmaxb[row] = m; rsumb[row] = 1.0f / s; }
}

// ---------------- context partials: ctxp[part][bh][d*32+e], n split 8 ways
__global__ __launch_bounds__(256) void k_ctx(const ushort* __restrict__ qkv,
        const float* __restrict__ memkv, const float* __restrict__ kmaxb,
        const float* __restrict__ rsumb, float* __restrict__ ctxp) {
    __shared__ float kl[DH][65];
    __shared__ float vl[DH][65];
    __shared__ float red[256 * 33];
    int tid = threadIdx.x;
    int bh = blockIdx.x;            // 0..127
    int part = blockIdx.y;          // 0..7
    int b = bh >> 2, h = bh & 3;
    int lr = tid >> 3;              // 0..31: k/v row this thread stages
    int nn8 = (tid & 7) * 8;        // 8-col chunk
    const ushort* kp = qkv + ((size_t)(b * OC3 + HID + h * DH) + lr) * HW + part * 512 + nn8;
    const ushort* vp = qkv + ((size_t)(b * OC3 + 2 * HID + h * DH) + lr) * HW + part * 512 + nn8;
    int rowbase = bh * DH;
    float kmr = kmaxb[rowbase + lr], rsr = rsumb[rowbase + lr];
    int slot = tid & 31, nng = tid >> 5;
    int d0 = (slot >> 2) * 4, e0 = (slot & 3) * 8;
    float acc[4][8];
    #pragma unroll
    for (int i = 0; i < 4; ++i)
        #pragma unroll
        for (int j = 0; j < 8; ++j) acc[i][j] = 0.f;
    for (int n0 = 0; n0 < 512; n0 += 64) {
        __syncthreads();
        uint4 kv4 = *(const uint4*)&kp[n0];
        uint4 vv4 = *(const uint4*)&vp[n0];
        const ushort* ke = (const ushort*)&kv4;
        const ushort* ve = (const ushort*)&vv4;
        #pragma unroll
        for (int j = 0; j < 8; ++j) {
            kl[lr][nn8 + j] = __expf(bf2f(ke[j]) - kmr) * rsr;
            vl[lr][nn8 + j] = bf2f(ve[j]);
        }
        __syncthreads();
        #pragma unroll 2
        for (int t = 0; t < 8; ++t) {
            int nn = nng * 8 + t;
            float kv[4], vv[8];
            #pragma unroll
            for (int i = 0; i < 4; ++i) kv[i] = kl[d0 + i][nn];
            #pragma unroll
            for (int j = 0; j < 8; ++j) vv[j] = vl[e0 + j][nn];
            #pragma unroll
            for (int i = 0; i < 4; ++i)
                #pragma unroll
                for (int j = 0; j < 8; ++j) acc[i][j] += kv[i] * vv[j];
        }
    }
    __syncthreads();
    #pragma unroll
    for (int i = 0; i < 4; ++i)
        #pragma unroll
        for (int j = 0; j < 8; ++j) red[tid * 33 + i * 8 + j] = acc[i][j];
    __syncthreads();
    #pragma unroll
    for (int q = 0; q < 4; ++q) {
        int o = tid * 4 + q;
        int d = o >> 5, e = o & 31;
        int sl = (d >> 2) * 4 + (e >> 3);
        int k = (d & 3) * 8 + (e & 7);
        float s = 0.f;
        #pragma unroll
        for (int g = 0; g < 8; ++g) s += red[(g * 32 + sl) * 33 + k];
        if (part == 0) {   // memory-kv contribution added once
            float km = kmaxb[rowbase + d], rsm = rsumb[rowbase + d];
            #pragma unroll
            for (int m = 0; m < NM; ++m) {
                float kw = __expf(memkv[(h * DH + d) * NM + m] - km) * rsm;
                s += kw * memkv[512 + (h * DH + e) * NM + m];
            }
        }
        ctxp[(size_t)part * 131072 + (size_t)bh * 1024 + o] = s;
    }
}

// ---------------- fold ctx into out-proj weight, once per batch:
// W2[b][oc][h*32+d] = sum_e wout[oc][h*32+e] * ctx_b[h][d][e]   (bf16)
__global__ __launch_bounds__(256) void k_w2(const float* __restrict__ ctxp,
        const ushort* __restrict__ woutt, ushort* __restrict__ W2) {
    __shared__ ushort ctxb[4 * 32 * 40];   // [h][d][e], pad 40 (80B rows, 16B-aligned)
    int tid = threadIdx.x, b = blockIdx.x;
    int wid = tid >> 6;
    int l15 = tid & 15, quad = (tid >> 4) & 3;
    #pragma unroll
    for (int j = 0; j < 16; ++j) {
        int idx = tid + j * 256;            // 0..4095 = h*1024 + d*32 + e
        float s = 0.f;
        #pragma unroll
        for (int p = 0; p < NPART; ++p)
            s += ctxp[(size_t)p * 131072 + (size_t)b * 4096 + idx];
        int h = idx >> 10, d = (idx >> 5) & 31, e = idx & 31;
        ctxb[(h * 32 + d) * 40 + e] = f2bf(s);
    }
    __syncthreads();
    #pragma unroll
    for (int h = 0; h < 4; ++h) {
        f32x4 acc[4][2];
        #pragma unroll
        for (int i = 0; i < 4; ++i)
            #pragma unroll
            for (int j = 0; j < 2; ++j) acc[i][j] = (f32x4){0.f, 0.f, 0.f, 0.f};
        bf16x8 af[4], bfr[2];
        #pragma unroll
        for (int mt = 0; mt < 4; ++mt)
            af[mt] = *(const bf16x8*)&woutt[(size_t)(wid * 64 + mt * 16 + l15) * HID
                                            + h * DH + quad * 8];
        #pragma unroll
        for (int nt = 0; nt < 2; ++nt)
            bfr[nt] = *(const bf16x8*)&ctxb[(h * 32 + nt * 16 + l15) * 40 + quad * 8];
        #pragma unroll
        for (int mt = 0; mt < 4; ++mt)
            #pragma unroll
            for (int nt = 0; nt < 2; ++nt)
                acc[mt][nt] = __builtin_amdgcn_mfma_f32_16x16x32_bf16(
                                  af[mt], bfr[nt], acc[mt][nt], 0, 0, 0);
        #pragma unroll
        for (int mt = 0; mt < 4; ++mt)
            #pragma unroll
            for (int nt = 0; nt < 2; ++nt)
                #pragma unroll
                for (int r = 0; r < 4; ++r) {
                    int oc = wid * 64 + mt * 16 + quad * 4 + r;
                    int d  = nt * 16 + l15;
                    W2[((size_t)b * CC + oc) * HID + h * DH + d] = f2bf(acc[mt][nt][r]);
                }
    }
}

// ---------------- final v2: q staged via g2l16 (was 32 strided loads/thread),
// Ws source-XOR-swizzled (was 8-way conflict), qs aliases Ws (3 blocks/CU kept)
__global__ __launch_bounds__(256) void k_final(const ushort* __restrict__ qkv,
        const ushort* __restrict__ W2, const float* __restrict__ bout,
        const float* __restrict__ g2, float* __restrict__ y) {
    __shared__ __align__(16) ushort sq[64 * 136];   // [pix][hid] softmaxed q
    __shared__ __align__(16) ushort WsQ[256 * 32];  // Ws tile; aliases q-stage qs[128][64]
    __shared__ float red[64 * 17];
    __shared__ float invs[64];
    __shared__ float bl[256];
    __shared__ float gl[256];
    int tid = threadIdx.x;
    int b = blockIdx.y;
    int hwb = blockIdx.x * 64;
    int lane = tid & 63, wid = tid >> 6;
    int l15 = tid & 15, quad = (tid >> 4) & 3;
    bl[tid] = bout[tid];
    gl[tid] = g2[tid];

    // ---- stage q tile [hid=128][pix=64] into WsQ (as qs), coalesced
    {
        const ushort* qb = qkv + ((size_t)b * OC3) * HW + hwb;
        #pragma unroll
        for (int pass = 0; pass < 4; ++pass) {
            int r0 = pass * 32 + wid * 8;                 // 8 rows per wave per pass
            int row = r0 + (lane >> 3);
            g2l16(qb + (size_t)row * HW + (lane & 7) * 8, &WsQ[r0 * 64]);
        }
    }
    __syncthreads();

    // ---- softmax over d per (h=wid, pix=lane); write sq[pix][hid] bf16
    {
        float vd[32];
        float m = -1e30f;
        #pragma unroll
        for (int d = 0; d < 32; ++d) {
            float v = bf2f(WsQ[(wid * 32 + d) * 64 + lane]);
            vd[d] = v; m = fmaxf(m, v);
        }
        float s = 0.f;
        #pragma unroll
        for (int d = 0; d < 32; ++d) { float e = __expf(vd[d] - m); vd[d] = e; s += e; }
        float r_ = SCALE / s;
        #pragma unroll
        for (int q8 = 0; q8 < 4; ++q8) {
            uint4 pk; ushort* o8 = (ushort*)&pk;
            #pragma unroll
            for (int i = 0; i < 8; ++i) o8[i] = f2bf(vd[q8 * 8 + i] * r_);
            *(uint4*)&sq[lane * 136 + wid * DH + q8 * 8] = pk;
        }
    }

    // ---- GEMM: y0[256 oc][64 pix] = W2_b[256][128] @ sq^T, K=128 in 4 steps
    f32x4 acc[4][4];
    #pragma unroll
    for (int i = 0; i < 4; ++i)
        #pragma unroll
        for (int j = 0; j < 4; ++j) acc[i][j] = (f32x4){0.f, 0.f, 0.f, 0.f};
    int rsub = lane >> 2;
    const ushort* W2b = W2 + (size_t)b * CC * HID;
    for (int k0 = 0; k0 < HID; k0 += 32) {
        __syncthreads();    // iter0: guards sq writes + last qs read before Ws overwrite
        #pragma unroll
        for (int q = 0; q < 4; ++q) {
            int rw = wid * 64 + q * 16;
            int r  = rw + rsub;
            int sc = (lane & 3) ^ ((r >> 1) & 3);   // pre-swizzled source chunk
            g2l16(W2b + (size_t)r * HID + k0 + sc * 8, &WsQ[rw * 32]);
        }
        __syncthreads();
        bf16x8 af[4], bfr[4];
        #pragma unroll
        for (int mt = 0; mt < 4; ++mt) {
            int ra = wid * 64 + mt * 16 + l15;
            af[mt] = *(const bf16x8*)&WsQ[ra * 32 + ((quad ^ ((ra >> 1) & 3)) << 3)];
        }
        #pragma unroll
        for (int nt = 0; nt < 4; ++nt)
            bfr[nt] = *(const bf16x8*)&sq[(nt * 16 + l15) * 136 + k0 + quad * 8];
        #pragma unroll
        for (int mt = 0; mt < 4; ++mt)
            #pragma unroll
            for (int nt = 0; nt < 4; ++nt)
                acc[mt][nt] = __builtin_amdgcn_mfma_f32_16x16x32_bf16(
                                  af[mt], bfr[nt], acc[mt][nt], 0, 0, 0);
    }

    // ---- epilogue: bias, rms-norm over 256 oc, *g2*16
    float part[4] = {0.f, 0.f, 0.f, 0.f};
    #pragma unroll
    for (int mt = 0; mt < 4; ++mt)
        #pragma unroll
        for (int r = 0; r < 4; ++r) {
            int oc = wid * 64 + mt * 16 + quad * 4 + r;
            float bo = bl[oc];
            #pragma unroll
            for (int nt = 0; nt < 4; ++nt) {
                float v = acc[mt][nt][r] + bo;
                acc[mt][nt][r] = v;
                part[nt] += v * v;
            }
        }
    __syncthreads();
    #pragma unroll
    for (int nt = 0; nt < 4; ++nt)
        red[(nt * 16 + l15) * 17 + wid * 4 + quad] = part[nt];
    __syncthreads();
    if (tid < 64) {
        float s = 0.f;
        #pragma unroll
        for (int g = 0; g < 16; ++g) s += red[tid * 17 + g];
        invs[tid] = 1.0f / fmaxf(sqrtf(s), 1e-12f);
    }
    __syncthreads();
    #pragma unroll
    for (int mt = 0; mt < 4; ++mt)
        #pragma unroll
        for (int nt = 0; nt < 4; ++nt) {
            int pix = nt * 16 + l15;
            float iv = invs[pix];
            #pragma unroll
            for (int r = 0; r < 4; ++r) {
                int oc = wid * 64 + mt * 16 + quad * 4 + r;
                y[((size_t)(b * CC + oc)) * HW + hwb + pix] = acc[mt][nt][r] * iv * gl[oc] * 16.0f;
            }
        }
}

extern "C" void kernel_launch(void* const* d_in, const int* in_sizes, int n_in,
                              void* d_out, int out_size, void* d_ws, size_t ws_size,
                              hipStream_t stream) {
    const float* x     = (const float*)d_in[0];
    const float* g1    = (const float*)d_in[1];
    const float* memkv = (const float*)d_in[2];
    const float* wqkv  = (const float*)d_in[3];
    const float* wout  = (const float*)d_in[4];
    const float* bout  = (const float*)d_in[5];
    const float* g2    = (const float*)d_in[6];
    float* y = (float*)d_out;

    char* w = (char*)d_ws;
    ushort* wq2t  = (ushort*)w;  w += (size_t)OC3 * CC * 2;
    ushort* woutt = (ushort*)w;  w += (size_t)CC * HID * 2;
    float*  kmaxb = (float*)w;   w += 4096 * 4;
    float*  rsumb = (float*)w;   w += 4096 * 4;
    float*  ctxp  = (float*)w;   w += (size_t)NPART * 131072 * 4;  // 4 MB
    ushort* W2    = (ushort*)w;  w += (size_t)32 * CC * HID * 2;   // 2 MB
    ushort* xnT   = (ushort*)w;  w += (size_t)32 * HW * CC * 2;    // 67 MB
    ushort* qkv   = (ushort*)w;  w += (size_t)32 * OC3 * HW * 2;   // 100 MB

    k_xn    <<<dim3(4096),      dim3(256), 0, stream>>>(x, wqkv, g1, wout, wq2t, woutt, xnT);
    k_qkv   <<<dim3(3, 32, 32), dim3(256), 0, stream>>>(wq2t, xnT, qkv);
    k_ksoft <<<dim3(1024),      dim3(256), 0, stream>>>(qkv, memkv, kmaxb, rsumb);
    k_ctx   <<<dim3(128, 8),    dim3(256), 0, stream>>>(qkv, memkv, kmaxb, rsumb, ctxp);
    k_w2    <<<dim3(32),        dim3(256), 0, stream>>>(ctxp, woutt, W2);
    k_final <<<dim3(64, 32),    dim3(256), 0, stream>>>(qkv, W2, bout, g2, y);
}

// Round 9
// 353.930 us; speedup vs baseline: 1.1936x; 1.0343x over previous
//
#include <hip/hip_runtime.h>
#include <math.h>

#define CC   256
#define HW   4096
#define OC3  384
#define HID  128
#define DH   32
#define NM   4
#define NPART 8
#define SCALE 0.17677669529663688f  // 32^-0.5

typedef __bf16 bf16x8 __attribute__((ext_vector_type(8)));
typedef float  f32x4  __attribute__((ext_vector_type(4)));

__device__ __forceinline__ ushort f2bf(float x) {
    union { float f; unsigned u; } v; v.f = x;
    unsigned r = v.u + 0x7fffu + ((v.u >> 16) & 1u);   // RNE
    return (ushort)(r >> 16);
}
__device__ __forceinline__ float bf2f(ushort b) {
    union { unsigned u; float f; } v; v.u = ((unsigned)b) << 16; return v.f;
}
__device__ __forceinline__ void g2l16(const void* g, void* l) {
    __builtin_amdgcn_global_load_lds(
        (const __attribute__((address_space(1))) void*)g,
        (__attribute__((address_space(3))) void*)l, 16, 0, 0);
}

// ---------------- fused rms-norm + transpose + bf16: xnT[b][pix][c]
// float4 global loads; LDS stride 36. k_prep merged (blocks 0..383).
__global__ __launch_bounds__(256) void k_xn(const float* __restrict__ x,
        const float* __restrict__ wqkv, const float* __restrict__ g1,
        const float* __restrict__ wout,
        ushort* __restrict__ wq2t, ushort* __restrict__ woutt,
        ushort* __restrict__ xnT) {
    __shared__ float xt[256 * 36];
    __shared__ float ps[8 * 33];
    __shared__ float invn[32];
    int tid = threadIdx.x;
    if (blockIdx.x < 384) {           // merged k_prep
        int o = blockIdx.x;
        wq2t[(size_t)o * CC + tid] = f2bf(wqkv[(size_t)o * CC + tid] * g1[tid] * 16.0f);
        if (o < CC && tid < HID) woutt[(size_t)o * HID + tid] = f2bf(wout[(size_t)o * HID + tid]);
    }
    int pix0 = blockIdx.x * 32;
    int b = pix0 >> 12, hw0 = pix0 & 4095;
    int p = tid & 31, cg = tid >> 5;
    const float* xb = x + (size_t)b * CC * HW + hw0;
    {
        int cr = tid >> 3;
        int chunk = tid & 7;
        #pragma unroll
        for (int pass = 0; pass < 8; ++pass) {
            int c = pass * 32 + cr;
            float4 v = *(const float4*)&xb[(size_t)c * HW + chunk * 4];
            *(float4*)&xt[c * 36 + chunk * 4] = v;
        }
    }
    __syncthreads();
    float s = 0.f;
    #pragma unroll 8
    for (int i = 0; i < 32; ++i) { float v = xt[(cg * 32 + i) * 36 + p]; s += v * v; }
    ps[cg * 33 + p] = s;
    __syncthreads();
    if (tid < 32) {
        float t = 0.f;
        #pragma unroll
        for (int g = 0; g < 8; ++g) t += ps[g * 33 + tid];
        invn[tid] = 1.0f / fmaxf(sqrtf(t), 1e-12f);
    }
    __syncthreads();
    float inv = invn[p];
    ushort* dst = xnT + ((size_t)(pix0 + p)) * CC + cg * 32;
    #pragma unroll
    for (int q = 0; q < 4; ++q) {
        uint4 pk; ushort* o8 = (ushort*)&pk;
        #pragma unroll
        for (int i = 0; i < 8; ++i) o8[i] = f2bf(xt[(cg * 32 + q * 8 + i) * 36 + p] * inv);
        *(uint4*)&dst[q * 8] = pk;
    }
}

// ---------------- qkv MFMA GEMM (R7/R8 structure, verified 0-conflict)
__global__ __launch_bounds__(256) void k_qkv(const ushort* __restrict__ wq2t,
        const ushort* __restrict__ xnT, ushort* __restrict__ qkv) {
    __shared__ __align__(16) ushort As[2][128 * 32];
    __shared__ __align__(16) ushort Bs[2][128 * 32];
    int tid = threadIdx.x;
    int lin = blockIdx.x + 3 * (blockIdx.y + 32 * blockIdx.z);   // 0..3071
    int swz = (lin & 7) * 384 + (lin >> 3);                      // XCD-bijective
    int m0 = (swz % 3) * 128;
    int t_ = swz / 3;
    int p0 = (t_ & 31) * 128;
    int b  = t_ >> 5;
    int lane = tid & 63, wid = tid >> 6;
    int l15 = tid & 15, quad = (tid >> 4) & 3;
    int wm = wid >> 1, wn = wid & 1;
    int rsub = lane >> 2;
    const ushort* Ab = wq2t + (size_t)m0 * CC;
    const ushort* Bb = xnT + ((size_t)(b * HW + p0)) * CC;
    f32x4 acc[4][4];
    #pragma unroll
    for (int i = 0; i < 4; ++i)
        #pragma unroll
        for (int j = 0; j < 4; ++j) acc[i][j] = (f32x4){0.f, 0.f, 0.f, 0.f};

    auto stage = [&](int buf, int k0) {
        #pragma unroll
        for (int q = 0; q < 2; ++q) {
            int rw = wid * 32 + q * 16;
            int r  = rw + rsub;
            int sc = (lane & 3) ^ ((r >> 1) & 3);
            g2l16(Ab + (size_t)r * CC + k0 + sc * 8, &As[buf][rw * 32]);
            g2l16(Bb + (size_t)r * CC + k0 + sc * 8, &Bs[buf][rw * 32]);
        }
    };

    stage(0, 0);
    __syncthreads();
    #pragma unroll
    for (int s = 0; s < 8; ++s) {
        int cur = s & 1;
        if (s < 7) stage(cur ^ 1, (s + 1) * 32);
        bf16x8 af[4], bfr[4];
        #pragma unroll
        for (int mt = 0; mt < 4; ++mt) {
            int ra = wm * 64 + mt * 16 + l15;
            af[mt] = *(const bf16x8*)&As[cur][ra * 32 + ((quad ^ ((ra >> 1) & 3)) << 3)];
        }
        #pragma unroll
        for (int nt = 0; nt < 4; ++nt) {
            int rb = wn * 64 + nt * 16 + l15;
            bfr[nt] = *(const bf16x8*)&Bs[cur][rb * 32 + ((quad ^ ((rb >> 1) & 3)) << 3)];
        }
        #pragma unroll
        for (int mt = 0; mt < 4; ++mt)
            #pragma unroll
            for (int nt = 0; nt < 4; ++nt)
                acc[mt][nt] = __builtin_amdgcn_mfma_f32_16x16x32_bf16(
                                  af[mt], bfr[nt], acc[mt][nt], 0, 0, 0);
        __syncthreads();
    }
    #pragma unroll
    for (int mt = 0; mt < 4; ++mt) {
        int o = m0 + wm * 64 + mt * 16 + quad * 4;
        #pragma unroll
        for (int nt = 0; nt < 4; ++nt) {
            int pix = p0 + wn * 64 + nt * 16 + l15;
            ushort* dst = qkv + ((size_t)(b * OC3 + o)) * HW + pix;
            #pragma unroll
            for (int r = 0; r < 4; ++r) dst[(size_t)r * HW] = f2bf(acc[mt][nt][r]);
        }
    }
}

// ---------------- k-softmax stats, v3: single memory pass (row cached in regs)
__global__ void k_ksoft(const ushort* __restrict__ qkv, const float* __restrict__ memkv,
                        float* __restrict__ kmaxb, float* __restrict__ rsumb) {
    int row = blockIdx.x * 4 + (threadIdx.x >> 6);
    int lane = threadIdx.x & 63;
    int b = row >> 7, hd = row & 127;
    const ushort* kp = qkv + ((size_t)(b * OC3 + HID + hd)) * HW;
    uint4 kreg[8];
    #pragma unroll
    for (int i = 0; i < 8; ++i) kreg[i] = *(const uint4*)&kp[i * 512 + lane * 8];
    float m = -1e30f;
    #pragma unroll
    for (int i = 0; i < 8; ++i) {
        const ushort* e = (const ushort*)&kreg[i];
        #pragma unroll
        for (int j = 0; j < 8; ++j) m = fmaxf(m, bf2f(e[j]));
    }
    #pragma unroll
    for (int s = 1; s < 64; s <<= 1) m = fmaxf(m, __shfl_xor(m, s));
    const float* mk = memkv + hd * NM;
    #pragma unroll
    for (int j = 0; j < NM; ++j) m = fmaxf(m, mk[j]);
    float s = 0.f;
    #pragma unroll
    for (int i = 0; i < 8; ++i) {
        const ushort* e = (const ushort*)&kreg[i];
        #pragma unroll
        for (int j = 0; j < 8; ++j) s += __expf(bf2f(e[j]) - m);
    }
    #pragma unroll
    for (int t = 1; t < 64; t <<= 1) s += __shfl_xor(s, t);
    #pragma unroll
    for (int j = 0; j < NM; ++j) s += __expf(mk[j] - m);
    if (lane == 0) { kmaxb[row] = m; rsumb[row] = 1.0f / s; }
}

// ---------------- context partials, v3: MFMA (was VALU outer-product, LDS-bound)
// Per wave: 2 independent 64-n chunks; kl (exp-weighted, bf16) and vl staged in
// per-wave LDS tiles with XOR-swizzled 128B rows; 2 K-steps x 2x2 MFMA tiles.
// Single barrier pair for the 4-way cross-wave reduction (red aliases kl).
__global__ __launch_bounds__(256) void k_ctx(const ushort* __restrict__ qkv,
        const float* __restrict__ memkv, const float* __restrict__ kmaxb,
        const float* __restrict__ rsumb, float* __restrict__ ctxp) {
    __shared__ __align__(16) char smem[32768];
    ushort* klw = (ushort*)smem;             // [4 waves][32 d][64 n] bf16, swizzled
    ushort* vlw = (ushort*)(smem + 16384);   // [4 waves][32 e][64 n]
    float*  red = (float*)smem;              // [4][1024] aliases klw (dead after MFMA)
    int tid = threadIdx.x;
    int lane = tid & 63, wid = tid >> 6;
    int l15 = lane & 15, quad = lane >> 4;
    int bh = blockIdx.x, part = blockIdx.y;
    int b = bh >> 2, h = bh & 3;
    int rowbase = bh * DH;
    int r  = lane >> 1;                 // staged row 0..31 (2 lanes/row)
    int ch = (lane & 1) * 32;           // 32-elem col chunk base
    const ushort* kp = qkv + ((size_t)(b * OC3 + HID + h * DH) + r) * HW + part * 512;
    const ushort* vp = qkv + ((size_t)(b * OC3 + 2 * HID + h * DH) + r) * HW + part * 512;
    float kmr = kmaxb[rowbase + r], rsr = rsumb[rowbase + r];
    ushort* myk = klw + wid * 2048;
    ushort* myv = vlw + wid * 2048;
    f32x4 acc[2][2];
    #pragma unroll
    for (int i = 0; i < 2; ++i)
        #pragma unroll
        for (int j = 0; j < 2; ++j) acc[i][j] = (f32x4){0.f, 0.f, 0.f, 0.f};

    #pragma unroll
    for (int t = 0; t < 2; ++t) {
        int n0 = wid * 64 + t * 256;
        #pragma unroll
        for (int i = 0; i < 4; ++i) {
            uint4 kv4 = *(const uint4*)&kp[n0 + ch + i * 8];
            uint4 vv4 = *(const uint4*)&vp[n0 + ch + i * 8];
            uint4 ko; ushort* kw = (ushort*)&ko; const ushort* ke = (const ushort*)&kv4;
            #pragma unroll
            for (int j = 0; j < 8; ++j) kw[j] = f2bf(__expf(bf2f(ke[j]) - kmr) * rsr);
            int boff = ((ch + i * 8) * 2) ^ ((r & 7) << 4);   // byte off in 128B row
            *(uint4*)((char*)&myk[r * 64] + boff) = ko;
            *(uint4*)((char*)&myv[r * 64] + boff) = vv4;
        }
        #pragma unroll
        for (int ks = 0; ks < 2; ++ks) {
            bf16x8 af[2], bf[2];
            #pragma unroll
            for (int dt = 0; dt < 2; ++dt) {
                int row = dt * 16 + l15;
                int boff = (ks * 64 + quad * 16) ^ ((row & 7) << 4);
                af[dt] = *(const bf16x8*)((char*)&myk[row * 64] + boff);
                bf[dt] = *(const bf16x8*)((char*)&myv[row * 64] + boff);
            }
            #pragma unroll
            for (int dt = 0; dt < 2; ++dt)
                #pragma unroll
                for (int et = 0; et < 2; ++et)
                    acc[dt][et] = __builtin_amdgcn_mfma_f32_16x16x32_bf16(
                                      af[dt], bf[et], acc[dt][et], 0, 0, 0);
        }
    }
    __syncthreads();   // all kl/vl reads done; red (aliases kl) safe to write
    #pragma unroll
    for (int dt = 0; dt < 2; ++dt)
        #pragma unroll
        for (int et = 0; et < 2; ++et)
            #pragma unroll
            for (int rr = 0; rr < 4; ++rr) {
                int d = dt * 16 + quad * 4 + rr;
                int e = et * 16 + l15;
                red[wid * 1024 + d * 32 + e] = acc[dt][et][rr];
            }
    __syncthreads();
    {
        int o0 = tid * 4;
        f32x4 s4 = (f32x4){0.f, 0.f, 0.f, 0.f};
        #pragma unroll
        for (int w = 0; w < 4; ++w) {
            f32x4 v = *(const f32x4*)&red[w * 1024 + o0];
            s4[0] += v[0]; s4[1] += v[1]; s4[2] += v[2]; s4[3] += v[3];
        }
        if (part == 0) {   // memory-kv contribution added once
            int d = o0 >> 5;
            float km = kmaxb[rowbase + d], rsm = rsumb[rowbase + d];
            #pragma unroll
            for (int q = 0; q < 4; ++q) {
                int e = (o0 + q) & 31;
                #pragma unroll
                for (int m = 0; m < NM; ++m) {
                    float kw = __expf(memkv[(h * DH + d) * NM + m] - km) * rsm;
                    s4[q] += kw * memkv[512 + (h * DH + e) * NM + m];
                }
            }
        }
        *(f32x4*)&ctxp[(size_t)part * 131072 + (size_t)bh * 1024 + o0] = s4;
    }
}

// ---------------- fold ctx into out-proj weight, once per batch
__global__ __launch_bounds__(256) void k_w2(const float* __restrict__ ctxp,
        const ushort* __restrict__ woutt, ushort* __restrict__ W2) {
    __shared__ ushort ctxb[4 * 32 * 40];
    int tid = threadIdx.x, b = blockIdx.x;
    int wid = tid >> 6;
    int l15 = tid & 15, quad = (tid >> 4) & 3;
    #pragma unroll
    for (int j = 0; j < 16; ++j) {
        int idx = tid + j * 256;
        float s = 0.f;
        #pragma unroll
        for (int p = 0; p < NPART; ++p)
            s += ctxp[(size_t)p * 131072 + (size_t)b * 4096 + idx];
        int h = idx >> 10, d = (idx >> 5) & 31, e = idx & 31;
        ctxb[(h * 32 + d) * 40 + e] = f2bf(s);
    }
    __syncthreads();
    #pragma unroll
    for (int h = 0; h < 4; ++h) {
        f32x4 acc[4][2];
        #pragma unroll
        for (int i = 0; i < 4; ++i)
            #pragma unroll
            for (int j = 0; j < 2; ++j) acc[i][j] = (f32x4){0.f, 0.f, 0.f, 0.f};
        bf16x8 af[4], bfr[2];
        #pragma unroll
        for (int mt = 0; mt < 4; ++mt)
            af[mt] = *(const bf16x8*)&woutt[(size_t)(wid * 64 + mt * 16 + l15) * HID
                                            + h * DH + quad * 8];
        #pragma unroll
        for (int nt = 0; nt < 2; ++nt)
            bfr[nt] = *(const bf16x8*)&ctxb[(h * 32 + nt * 16 + l15) * 40 + quad * 8];
        #pragma unroll
        for (int mt = 0; mt < 4; ++mt)
            #pragma unroll
            for (int nt = 0; nt < 2; ++nt)
                acc[mt][nt] = __builtin_amdgcn_mfma_f32_16x16x32_bf16(
                                  af[mt], bfr[nt], acc[mt][nt], 0, 0, 0);
        #pragma unroll
        for (int mt = 0; mt < 4; ++mt)
            #pragma unroll
            for (int nt = 0; nt < 2; ++nt)
                #pragma unroll
                for (int r = 0; r < 4; ++r) {
                    int oc = wid * 64 + mt * 16 + quad * 4 + r;
                    int d  = nt * 16 + l15;
                    W2[((size_t)b * CC + oc) * HID + h * DH + d] = f2bf(acc[mt][nt][r]);
                }
    }
}

// ---------------- final: q staged via g2l16, Ws source-XOR-swizzled
__global__ __launch_bounds__(256) void k_final(const ushort* __restrict__ qkv,
        const ushort* __restrict__ W2, const float* __restrict__ bout,
        const float* __restrict__ g2, float* __restrict__ y) {
    __shared__ __align__(16) ushort sq[64 * 136];
    __shared__ __align__(16) ushort WsQ[256 * 32];
    __shared__ float red[64 * 17];
    __shared__ float invs[64];
    __shared__ float bl[256];
    __shared__ float gl[256];
    int tid = threadIdx.x;
    int b = blockIdx.y;
    int hwb = blockIdx.x * 64;
    int lane = tid & 63, wid = tid >> 6;
    int l15 = tid & 15, quad = (tid >> 4) & 3;
    bl[tid] = bout[tid];
    gl[tid] = g2[tid];

    {
        const ushort* qb = qkv + ((size_t)b * OC3) * HW + hwb;
        #pragma unroll
        for (int pass = 0; pass < 4; ++pass) {
            int r0 = pass * 32 + wid * 8;
            int row = r0 + (lane >> 3);
            g2l16(qb + (size_t)row * HW + (lane & 7) * 8, &WsQ[r0 * 64]);
        }
    }
    __syncthreads();

    {
        float vd[32];
        float m = -1e30f;
        #pragma unroll
        for (int d = 0; d < 32; ++d) {
            float v = bf2f(WsQ[(wid * 32 + d) * 64 + lane]);
            vd[d] = v; m = fmaxf(m, v);
        }
        float s = 0.f;
        #pragma unroll
        for (int d = 0; d < 32; ++d) { float e = __expf(vd[d] - m); vd[d] = e; s += e; }
        float r_ = SCALE / s;
        #pragma unroll
        for (int q8 = 0; q8 < 4; ++q8) {
            uint4 pk; ushort* o8 = (ushort*)&pk;
            #pragma unroll
            for (int i = 0; i < 8; ++i) o8[i] = f2bf(vd[q8 * 8 + i] * r_);
            *(uint4*)&sq[lane * 136 + wid * DH + q8 * 8] = pk;
        }
    }

    f32x4 acc[4][4];
    #pragma unroll
    for (int i = 0; i < 4; ++i)
        #pragma unroll
        for (int j = 0; j < 4; ++j) acc[i][j] = (f32x4){0.f, 0.f, 0.f, 0.f};
    int rsub = lane >> 2;
    const ushort* W2b = W2 + (size_t)b * CC * HID;
    for (int k0 = 0; k0 < HID; k0 += 32) {
        __syncthreads();
        #pragma unroll
        for (int q = 0; q < 4; ++q) {
            int rw = wid * 64 + q * 16;
            int r  = rw + rsub;
            int sc = (lane & 3) ^ ((r >> 1) & 3);
            g2l16(W2b + (size_t)r * HID + k0 + sc * 8, &WsQ[rw * 32]);
        }
        __syncthreads();
        bf16x8 af[4], bfr[4];
        #pragma unroll
        for (int mt = 0; mt < 4; ++mt) {
            int ra = wid * 64 + mt * 16 + l15;
            af[mt] = *(const bf16x8*)&WsQ[ra * 32 + ((quad ^ ((ra >> 1) & 3)) << 3)];
        }
        #pragma unroll
        for (int nt = 0; nt < 4; ++nt)
            bfr[nt] = *(const bf16x8*)&sq[(nt * 16 + l15) * 136 + k0 + quad * 8];
        #pragma unroll
        for (int mt = 0; mt < 4; ++mt)
            #pragma unroll
            for (int nt = 0; nt < 4; ++nt)
                acc[mt][nt] = __builtin_amdgcn_mfma_f32_16x16x32_bf16(
                                  af[mt], bfr[nt], acc[mt][nt], 0, 0, 0);
    }

    float part[4] = {0.f, 0.f, 0.f, 0.f};
    #pragma unroll
    for (int mt = 0; mt < 4; ++mt)
        #pragma unroll
        for (int r = 0; r < 4; ++r) {
            int oc = wid * 64 + mt * 16 + quad * 4 + r;
            float bo = bl[oc];
            #pragma unroll
            for (int nt = 0; nt < 4; ++nt) {
                float v = acc[mt][nt][r] + bo;
                acc[mt][nt][r] = v;
                part[nt] += v * v;
            }
        }
    __syncthreads();
    #pragma unroll
    for (int nt = 0; nt < 4; ++nt)
        red[(nt * 16 + l15) * 17 + wid * 4 + quad] = part[nt];
    __syncthreads();
    if (tid < 64) {
        float s = 0.f;
        #pragma unroll
        for (int g = 0; g < 16; ++g) s += red[tid * 17 + g];
        invs[tid] = 1.0f / fmaxf(sqrtf(s), 1e-12f);
    }
    __syncthreads();
    #pragma unroll
    for (int mt = 0; mt < 4; ++mt)
        #pragma unroll
        for (int nt = 0; nt < 4; ++nt) {
            int pix = nt * 16 + l15;
            float iv = invs[pix];
            #pragma unroll
            for (int r = 0; r < 4; ++r) {
                int oc = wid * 64 + mt * 16 + quad * 4 + r;
                y[((size_t)(b * CC + oc)) * HW + hwb + pix] = acc[mt][nt][r] * iv * gl[oc] * 16.0f;
            }
        }
}

extern "C" void kernel_launch(void* const* d_in, const int* in_sizes, int n_in,
                              void* d_out, int out_size, void* d_ws, size_t ws_size,
                              hipStream_t stream) {
    const float* x     = (const float*)d_in[0];
    const float* g1    = (const float*)d_in[1];
    const float* memkv = (const float*)d_in[2];
    const float* wqkv  = (const float*)d_in[3];
    const float* wout  = (const float*)d_in[4];
    const float* bout  = (const float*)d_in[5];
    const float* g2    = (const float*)d_in[6];
    float* y = (float*)d_out;

    char* w = (char*)d_ws;
    ushort* wq2t  = (ushort*)w;  w += (size_t)OC3 * CC * 2;
    ushort* woutt = (ushort*)w;  w += (size_t)CC * HID * 2;
    float*  kmaxb = (float*)w;   w += 4096 * 4;
    float*  rsumb = (float*)w;   w += 4096 * 4;
    float*  ctxp  = (float*)w;   w += (size_t)NPART * 131072 * 4;  // 4 MB
    ushort* W2    = (ushort*)w;  w += (size_t)32 * CC * HID * 2;   // 2 MB
    ushort* xnT   = (ushort*)w;  w += (size_t)32 * HW * CC * 2;    // 67 MB
    ushort* qkv   = (ushort*)w;  w += (size_t)32 * OC3 * HW * 2;   // 100 MB

    k_xn    <<<dim3(4096),      dim3(256), 0, stream>>>(x, wqkv, g1, wout, wq2t, woutt, xnT);
    k_qkv   <<<dim3(3, 32, 32), dim3(256), 0, stream>>>(wq2t, xnT, qkv);
    k_ksoft <<<dim3(1024),      dim3(256), 0, stream>>>(qkv, memkv, kmaxb, rsumb);
    k_ctx   <<<dim3(128, 8),    dim3(256), 0, stream>>>(qkv, memkv, kmaxb, rsumb, ctxp);
    k_w2    <<<dim3(32),        dim3(256), 0, stream>>>(ctxp, woutt, W2);
    k_final <<<dim3(64, 32),    dim3(256), 0, stream>>>(qkv, W2, bout, g2, y);
}

// Round 10
// 353.428 us; speedup vs baseline: 1.1953x; 1.0014x over previous
//
#include <hip/hip_runtime.h>
#include <math.h>

#define CC   256
#define HW   4096
#define OC3  384
#define HID  128
#define DH   32
#define NM   4
#define NPART 8
#define SCALE 0.17677669529663688f  // 32^-0.5

typedef __bf16 bf16x8 __attribute__((ext_vector_type(8)));
typedef float  f32x4  __attribute__((ext_vector_type(4)));

__device__ __forceinline__ ushort f2bf(float x) {
    union { float f; unsigned u; } v; v.f = x;
    unsigned r = v.u + 0x7fffu + ((v.u >> 16) & 1u);   // RNE
    return (ushort)(r >> 16);
}
__device__ __forceinline__ float bf2f(ushort b) {
    union { unsigned u; float f; } v; v.u = ((unsigned)b) << 16; return v.f;
}
__device__ __forceinline__ void g2l16(const void* g, void* l) {
    __builtin_amdgcn_global_load_lds(
        (const __attribute__((address_space(1))) void*)g,
        (__attribute__((address_space(3))) void*)l, 16, 0, 0);
}

// ---------------- fused rms-norm + transpose + bf16: xnT[b][pix][c]
// float4 global loads; LDS stride 36. k_prep merged (blocks 0..383).
__global__ __launch_bounds__(256) void k_xn(const float* __restrict__ x,
        const float* __restrict__ wqkv, const float* __restrict__ g1,
        const float* __restrict__ wout,
        ushort* __restrict__ wq2t, ushort* __restrict__ woutt,
        ushort* __restrict__ xnT) {
    __shared__ float xt[256 * 36];
    __shared__ float ps[8 * 33];
    __shared__ float invn[32];
    int tid = threadIdx.x;
    if (blockIdx.x < 384) {           // merged k_prep
        int o = blockIdx.x;
        wq2t[(size_t)o * CC + tid] = f2bf(wqkv[(size_t)o * CC + tid] * g1[tid] * 16.0f);
        if (o < CC && tid < HID) woutt[(size_t)o * HID + tid] = f2bf(wout[(size_t)o * HID + tid]);
    }
    int pix0 = blockIdx.x * 32;
    int b = pix0 >> 12, hw0 = pix0 & 4095;
    int p = tid & 31, cg = tid >> 5;
    const float* xb = x + (size_t)b * CC * HW + hw0;
    {
        int cr = tid >> 3;
        int chunk = tid & 7;
        #pragma unroll
        for (int pass = 0; pass < 8; ++pass) {
            int c = pass * 32 + cr;
            float4 v = *(const float4*)&xb[(size_t)c * HW + chunk * 4];
            *(float4*)&xt[c * 36 + chunk * 4] = v;
        }
    }
    __syncthreads();
    float s = 0.f;
    #pragma unroll 8
    for (int i = 0; i < 32; ++i) { float v = xt[(cg * 32 + i) * 36 + p]; s += v * v; }
    ps[cg * 33 + p] = s;
    __syncthreads();
    if (tid < 32) {
        float t = 0.f;
        #pragma unroll
        for (int g = 0; g < 8; ++g) t += ps[g * 33 + tid];
        invn[tid] = 1.0f / fmaxf(sqrtf(t), 1e-12f);
    }
    __syncthreads();
    float inv = invn[p];
    ushort* dst = xnT + ((size_t)(pix0 + p)) * CC + cg * 32;
    #pragma unroll
    for (int q = 0; q < 4; ++q) {
        uint4 pk; ushort* o8 = (ushort*)&pk;
        #pragma unroll
        for (int i = 0; i < 8; ++i) o8[i] = f2bf(xt[(cg * 32 + q * 8 + i) * 36 + p] * inv);
        *(uint4*)&dst[q * 8] = pk;
    }
}

// ---------------- k/v MFMA GEMM (q dropped: computed in k_final). Grid 2x32x32.
__global__ __launch_bounds__(256) void k_qkv(const ushort* __restrict__ wq2t,
        const ushort* __restrict__ xnT, ushort* __restrict__ qkv) {
    __shared__ __align__(16) ushort As[2][128 * 32];
    __shared__ __align__(16) ushort Bs[2][128 * 32];
    int tid = threadIdx.x;
    int lin = blockIdx.x + 2 * (blockIdx.y + 32 * blockIdx.z);   // 0..2047
    int swz = (lin & 7) * 256 + (lin >> 3);                      // XCD-bijective
    int m0 = 128 + (swz % 2) * 128;                              // k or v rows
    int t_ = swz / 2;
    int p0 = (t_ & 31) * 128;
    int b  = t_ >> 5;
    int lane = tid & 63, wid = tid >> 6;
    int l15 = tid & 15, quad = (tid >> 4) & 3;
    int wm = wid >> 1, wn = wid & 1;
    int rsub = lane >> 2;
    const ushort* Ab = wq2t + (size_t)m0 * CC;
    const ushort* Bb = xnT + ((size_t)(b * HW + p0)) * CC;
    f32x4 acc[4][4];
    #pragma unroll
    for (int i = 0; i < 4; ++i)
        #pragma unroll
        for (int j = 0; j < 4; ++j) acc[i][j] = (f32x4){0.f, 0.f, 0.f, 0.f};

    auto stage = [&](int buf, int k0) {
        #pragma unroll
        for (int q = 0; q < 2; ++q) {
            int rw = wid * 32 + q * 16;
            int r  = rw + rsub;
            int sc = (lane & 3) ^ ((r >> 1) & 3);
            g2l16(Ab + (size_t)r * CC + k0 + sc * 8, &As[buf][rw * 32]);
            g2l16(Bb + (size_t)r * CC + k0 + sc * 8, &Bs[buf][rw * 32]);
        }
    };

    stage(0, 0);
    __syncthreads();
    #pragma unroll
    for (int s = 0; s < 8; ++s) {
        int cur = s & 1;
        if (s < 7) stage(cur ^ 1, (s + 1) * 32);
        bf16x8 af[4], bfr[4];
        #pragma unroll
        for (int mt = 0; mt < 4; ++mt) {
            int ra = wm * 64 + mt * 16 + l15;
            af[mt] = *(const bf16x8*)&As[cur][ra * 32 + ((quad ^ ((ra >> 1) & 3)) << 3)];
        }
        #pragma unroll
        for (int nt = 0; nt < 4; ++nt) {
            int rb = wn * 64 + nt * 16 + l15;
            bfr[nt] = *(const bf16x8*)&Bs[cur][rb * 32 + ((quad ^ ((rb >> 1) & 3)) << 3)];
        }
        #pragma unroll
        for (int mt = 0; mt < 4; ++mt)
            #pragma unroll
            for (int nt = 0; nt < 4; ++nt)
                acc[mt][nt] = __builtin_amdgcn_mfma_f32_16x16x32_bf16(
                                  af[mt], bfr[nt], acc[mt][nt], 0, 0, 0);
        __syncthreads();
    }
    #pragma unroll
    for (int mt = 0; mt < 4; ++mt) {
        int o = m0 + wm * 64 + mt * 16 + quad * 4;
        #pragma unroll
        for (int nt = 0; nt < 4; ++nt) {
            int pix = p0 + wn * 64 + nt * 16 + l15;
            ushort* dst = qkv + ((size_t)(b * OC3 + o)) * HW + pix;
            #pragma unroll
            for (int r = 0; r < 4; ++r) dst[(size_t)r * HW] = f2bf(acc[mt][nt][r]);
        }
    }
}

// ---------------- k-softmax stats, single memory pass (row cached in regs)
__global__ void k_ksoft(const ushort* __restrict__ qkv, const float* __restrict__ memkv,
                        float* __restrict__ kmaxb, float* __restrict__ rsumb) {
    int row = blockIdx.x * 4 + (threadIdx.x >> 6);
    int lane = threadIdx.x & 63;
    int b = row >> 7, hd = row & 127;
    const ushort* kp = qkv + ((size_t)(b * OC3 + HID + hd)) * HW;
    uint4 kreg[8];
    #pragma unroll
    for (int i = 0; i < 8; ++i) kreg[i] = *(const uint4*)&kp[i * 512 + lane * 8];
    float m = -1e30f;
    #pragma unroll
    for (int i = 0; i < 8; ++i) {
        const ushort* e = (const ushort*)&kreg[i];
        #pragma unroll
        for (int j = 0; j < 8; ++j) m = fmaxf(m, bf2f(e[j]));
    }
    #pragma unroll
    for (int s = 1; s < 64; s <<= 1) m = fmaxf(m, __shfl_xor(m, s));
    const float* mk = memkv + hd * NM;
    #pragma unroll
    for (int j = 0; j < NM; ++j) m = fmaxf(m, mk[j]);
    float s = 0.f;
    #pragma unroll
    for (int i = 0; i < 8; ++i) {
        const ushort* e = (const ushort*)&kreg[i];
        #pragma unroll
        for (int j = 0; j < 8; ++j) s += __expf(bf2f(e[j]) - m);
    }
    #pragma unroll
    for (int t = 1; t < 64; t <<= 1) s += __shfl_xor(s, t);
    #pragma unroll
    for (int j = 0; j < NM; ++j) s += __expf(mk[j] - m);
    if (lane == 0) { kmaxb[row] = m; rsumb[row] = 1.0f / s; }
}

// ---------------- context partials via MFMA (R9 structure)
__global__ __launch_bounds__(256) void k_ctx(const ushort* __restrict__ qkv,
        const float* __restrict__ memkv, const float* __restrict__ kmaxb,
        const float* __restrict__ rsumb, float* __restrict__ ctxp) {
    __shared__ __align__(16) char smem[32768];
    ushort* klw = (ushort*)smem;
    ushort* vlw = (ushort*)(smem + 16384);
    float*  red = (float*)smem;
    int tid = threadIdx.x;
    int lane = tid & 63, wid = tid >> 6;
    int l15 = lane & 15, quad = lane >> 4;
    int bh = blockIdx.x, part = blockIdx.y;
    int b = bh >> 2, h = bh & 3;
    int rowbase = bh * DH;
    int r  = lane >> 1;
    int ch = (lane & 1) * 32;
    const ushort* kp = qkv + ((size_t)(b * OC3 + HID + h * DH) + r) * HW + part * 512;
    const ushort* vp = qkv + ((size_t)(b * OC3 + 2 * HID + h * DH) + r) * HW + part * 512;
    float kmr = kmaxb[rowbase + r], rsr = rsumb[rowbase + r];
    ushort* myk = klw + wid * 2048;
    ushort* myv = vlw + wid * 2048;
    f32x4 acc[2][2];
    #pragma unroll
    for (int i = 0; i < 2; ++i)
        #pragma unroll
        for (int j = 0; j < 2; ++j) acc[i][j] = (f32x4){0.f, 0.f, 0.f, 0.f};

    #pragma unroll
    for (int t = 0; t < 2; ++t) {
        int n0 = wid * 64 + t * 256;
        #pragma unroll
        for (int i = 0; i < 4; ++i) {
            uint4 kv4 = *(const uint4*)&kp[n0 + ch + i * 8];
            uint4 vv4 = *(const uint4*)&vp[n0 + ch + i * 8];
            uint4 ko; ushort* kw = (ushort*)&ko; const ushort* ke = (const ushort*)&kv4;
            #pragma unroll
            for (int j = 0; j < 8; ++j) kw[j] = f2bf(__expf(bf2f(ke[j]) - kmr) * rsr);
            int boff = ((ch + i * 8) * 2) ^ ((r & 7) << 4);
            *(uint4*)((char*)&myk[r * 64] + boff) = ko;
            *(uint4*)((char*)&myv[r * 64] + boff) = vv4;
        }
        #pragma unroll
        for (int ks = 0; ks < 2; ++ks) {
            bf16x8 af[2], bf[2];
            #pragma unroll
            for (int dt = 0; dt < 2; ++dt) {
                int row = dt * 16 + l15;
                int boff = (ks * 64 + quad * 16) ^ ((row & 7) << 4);
                af[dt] = *(const bf16x8*)((char*)&myk[row * 64] + boff);
                bf[dt] = *(const bf16x8*)((char*)&myv[row * 64] + boff);
            }
            #pragma unroll
            for (int dt = 0; dt < 2; ++dt)
                #pragma unroll
                for (int et = 0; et < 2; ++et)
                    acc[dt][et] = __builtin_amdgcn_mfma_f32_16x16x32_bf16(
                                      af[dt], bf[et], acc[dt][et], 0, 0, 0);
        }
    }
    __syncthreads();
    #pragma unroll
    for (int dt = 0; dt < 2; ++dt)
        #pragma unroll
        for (int et = 0; et < 2; ++et)
            #pragma unroll
            for (int rr = 0; rr < 4; ++rr) {
                int d = dt * 16 + quad * 4 + rr;
                int e = et * 16 + l15;
                red[wid * 1024 + d * 32 + e] = acc[dt][et][rr];
            }
    __syncthreads();
    {
        int o0 = tid * 4;
        f32x4 s4 = (f32x4){0.f, 0.f, 0.f, 0.f};
        #pragma unroll
        for (int w = 0; w < 4; ++w) {
            f32x4 v = *(const f32x4*)&red[w * 1024 + o0];
            s4[0] += v[0]; s4[1] += v[1]; s4[2] += v[2]; s4[3] += v[3];
        }
        if (part == 0) {
            int d = o0 >> 5;
            float km = kmaxb[rowbase + d], rsm = rsumb[rowbase + d];
            #pragma unroll
            for (int q = 0; q < 4; ++q) {
                int e = (o0 + q) & 31;
                #pragma unroll
                for (int m = 0; m < NM; ++m) {
                    float kw = __expf(memkv[(h * DH + d) * NM + m] - km) * rsm;
                    s4[q] += kw * memkv[512 + (h * DH + e) * NM + m];
                }
            }
        }
        *(f32x4*)&ctxp[(size_t)part * 131072 + (size_t)bh * 1024 + o0] = s4;
    }
}

// ---------------- fold ctx into out-proj weight, once per batch
__global__ __launch_bounds__(256) void k_w2(const float* __restrict__ ctxp,
        const ushort* __restrict__ woutt, ushort* __restrict__ W2) {
    __shared__ ushort ctxb[4 * 32 * 40];
    int tid = threadIdx.x, b = blockIdx.x;
    int wid = tid >> 6;
    int l15 = tid & 15, quad = (tid >> 4) & 3;
    #pragma unroll
    for (int j = 0; j < 16; ++j) {
        int idx = tid + j * 256;
        float s = 0.f;
        #pragma unroll
        for (int p = 0; p < NPART; ++p)
            s += ctxp[(size_t)p * 131072 + (size_t)b * 4096 + idx];
        int h = idx >> 10, d = (idx >> 5) & 31, e = idx & 31;
        ctxb[(h * 32 + d) * 40 + e] = f2bf(s);
    }
    __syncthreads();
    #pragma unroll
    for (int h = 0; h < 4; ++h) {
        f32x4 acc[4][2];
        #pragma unroll
        for (int i = 0; i < 4; ++i)
            #pragma unroll
            for (int j = 0; j < 2; ++j) acc[i][j] = (f32x4){0.f, 0.f, 0.f, 0.f};
        bf16x8 af[4], bfr[2];
        #pragma unroll
        for (int mt = 0; mt < 4; ++mt)
            af[mt] = *(const bf16x8*)&woutt[(size_t)(wid * 64 + mt * 16 + l15) * HID
                                            + h * DH + quad * 8];
        #pragma unroll
        for (int nt = 0; nt < 2; ++nt)
            bfr[nt] = *(const bf16x8*)&ctxb[(h * 32 + nt * 16 + l15) * 40 + quad * 8];
        #pragma unroll
        for (int mt = 0; mt < 4; ++mt)
            #pragma unroll
            for (int nt = 0; nt < 2; ++nt)
                acc[mt][nt] = __builtin_amdgcn_mfma_f32_16x16x32_bf16(
                                  af[mt], bfr[nt], acc[mt][nt], 0, 0, 0);
        #pragma unroll
        for (int mt = 0; mt < 4; ++mt)
            #pragma unroll
            for (int nt = 0; nt < 2; ++nt)
                #pragma unroll
                for (int r = 0; r < 4; ++r) {
                    int oc = wid * 64 + mt * 16 + quad * 4 + r;
                    int d  = nt * 16 + l15;
                    W2[((size_t)b * CC + oc) * HID + h * DH + d] = f2bf(acc[mt][nt][r]);
                }
    }
}

// ---------------- final v3: q computed IN-BLOCK (Wq @ xnT tile, MFMA) ->
// softmax on fp32 accs (shfl over quad groups) -> W2 GEMM -> bias+rms*g2.
// q never touches global memory. LDS 52KB -> 3 blocks/CU (aliased regions).
__global__ __launch_bounds__(256) void k_final(const ushort* __restrict__ xnT,
        const ushort* __restrict__ wq2t, const ushort* __restrict__ W2,
        const float* __restrict__ bout, const float* __restrict__ g2,
        float* __restrict__ y) {
    __shared__ __align__(16) char smem[52224];
    ushort* xnTs = (ushort*)smem;              // [64][128] (c-half staged twice)
    float*  red  = (float*)smem;               // aliases xnTs (dead after q GEMM)
    float*  invs = (float*)(smem + 4352);
    ushort* Qw   = (ushort*)(smem + 16384);    // [2][128*32] dbuf; aliased as WsQ
    ushort* sq   = (ushort*)(smem + 32768);    // [64][136]
    float*  bl   = (float*)(smem + 50176);
    float*  gl   = (float*)(smem + 51200);
    int tid = threadIdx.x;
    int b = blockIdx.y;
    int hwb = blockIdx.x * 64;
    int lane = tid & 63, wid = tid >> 6;
    int l15 = tid & 15, quad = (tid >> 4) & 3;
    int rsub = lane >> 2;
    bl[tid] = bout[tid];
    gl[tid] = g2[tid];

    // stage xnT tile half (64 pix rows x 128 c), source chunk-XOR c^(r&7)
    auto stageX = [&](int half) {
        const ushort* xb = xnT + ((size_t)(b * HW + hwb)) * CC + half * 128;
        #pragma unroll
        for (int qq = 0; qq < 4; ++qq) {
            int r0 = qq * 16 + wid * 4;
            int r  = r0 + (lane >> 4);
            int g  = (lane & 15) ^ (r & 7);
            g2l16(xb + (size_t)r * CC + g * 8, &xnTs[r0 * 128]);
        }
    };
    // stage q-weight K-tile [128][32], As-style XOR
    auto stageQ = [&](int buf, int k0) {
        #pragma unroll
        for (int qq = 0; qq < 2; ++qq) {
            int rw = wid * 32 + qq * 16;
            int r  = rw + rsub;
            int sc = (lane & 3) ^ ((r >> 1) & 3);
            g2l16(wq2t + (size_t)r * CC + k0 + sc * 8, &Qw[buf * 4096 + rw * 32]);
        }
    };

    // ---- q GEMM: q[128 oc][64 pix] = Wq[128][256] @ xnT_tile^T, K=256 in 8 steps
    f32x4 accq[2][4];
    #pragma unroll
    for (int i = 0; i < 2; ++i)
        #pragma unroll
        for (int j = 0; j < 4; ++j) accq[i][j] = (f32x4){0.f, 0.f, 0.f, 0.f};
    stageX(0);
    stageQ(0, 0);
    __syncthreads();
    #pragma unroll
    for (int s = 0; s < 8; ++s) {
        int cur = s & 1;
        if (s < 7 && s != 3) stageQ(cur ^ 1, (s + 1) * 32);
        bf16x8 af[2], bfr[4];
        #pragma unroll
        for (int mt = 0; mt < 2; ++mt) {
            int ra = wid * 32 + mt * 16 + l15;
            af[mt] = *(const bf16x8*)&Qw[cur * 4096 + ra * 32 + ((quad ^ ((ra >> 1) & 3)) << 3)];
        }
        int cread = (s & 3) * 4 + quad;
        #pragma unroll
        for (int nt = 0; nt < 4; ++nt) {
            int rb = nt * 16 + l15;
            bfr[nt] = *(const bf16x8*)&xnTs[rb * 128 + ((cread ^ (rb & 7)) << 3)];
        }
        #pragma unroll
        for (int mt = 0; mt < 2; ++mt)
            #pragma unroll
            for (int nt = 0; nt < 4; ++nt)
                accq[mt][nt] = __builtin_amdgcn_mfma_f32_16x16x32_bf16(
                                   af[mt], bfr[nt], accq[mt][nt], 0, 0, 0);
        if (s == 3) {
            __syncthreads();          // all half-0 xnTs reads done
            stageX(1);
            stageQ(cur ^ 1, 128);
        }
        __syncthreads();
    }

    // ---- softmax over d (wave wid = head wid): cross-quad shfl reduce
    #pragma unroll
    for (int nt = 0; nt < 4; ++nt) {
        float m = -1e30f;
        #pragma unroll
        for (int mt = 0; mt < 2; ++mt)
            #pragma unroll
            for (int r = 0; r < 4; ++r) m = fmaxf(m, accq[mt][nt][r]);
        m = fmaxf(m, __shfl_xor(m, 16));
        m = fmaxf(m, __shfl_xor(m, 32));
        float s = 0.f;
        float e[2][4];
        #pragma unroll
        for (int mt = 0; mt < 2; ++mt)
            #pragma unroll
            for (int r = 0; r < 4; ++r) { e[mt][r] = __expf(accq[mt][nt][r] - m); s += e[mt][r]; }
        s += __shfl_xor(s, 16);
        s += __shfl_xor(s, 32);
        float r_ = SCALE / s;
        int pix = nt * 16 + l15;
        #pragma unroll
        for (int mt = 0; mt < 2; ++mt)
            #pragma unroll
            for (int r = 0; r < 4; ++r)
                sq[pix * 136 + wid * 32 + mt * 16 + quad * 4 + r] = f2bf(e[mt][r] * r_);
    }

    // ---- W2 GEMM: y0[256 oc][64 pix] = W2_b[256][128] @ sq^T, K=128 in 4 steps
    ushort* WsQ = Qw;   // Qw dead
    f32x4 acc[4][4];
    #pragma unroll
    for (int i = 0; i < 4; ++i)
        #pragma unroll
        for (int j = 0; j < 4; ++j) acc[i][j] = (f32x4){0.f, 0.f, 0.f, 0.f};
    const ushort* W2b = W2 + (size_t)b * CC * HID;
    for (int k0 = 0; k0 < HID; k0 += 32) {
        __syncthreads();    // iter0: guards sq writes + last Qw reads
        #pragma unroll
        for (int q = 0; q < 4; ++q) {
            int rw = wid * 64 + q * 16;
            int r  = rw + rsub;
            int sc = (lane & 3) ^ ((r >> 1) & 3);
            g2l16(W2b + (size_t)r * HID + k0 + sc * 8, &WsQ[rw * 32]);
        }
        __syncthreads();
        bf16x8 af[4], bfr[4];
        #pragma unroll
        for (int mt = 0; mt < 4; ++mt) {
            int ra = wid * 64 + mt * 16 + l15;
            af[mt] = *(const bf16x8*)&WsQ[ra * 32 + ((quad ^ ((ra >> 1) & 3)) << 3)];
        }
        #pragma unroll
        for (int nt = 0; nt < 4; ++nt)
            bfr[nt] = *(const bf16x8*)&sq[(nt * 16 + l15) * 136 + k0 + quad * 8];
        #pragma unroll
        for (int mt = 0; mt < 4; ++mt)
            #pragma unroll
            for (int nt = 0; nt < 4; ++nt)
                acc[mt][nt] = __builtin_amdgcn_mfma_f32_16x16x32_bf16(
                                  af[mt], bfr[nt], acc[mt][nt], 0, 0, 0);
    }

    // ---- epilogue: bias, rms-norm over 256 oc, *g2*16 (red aliases xnTs, dead)
    float part[4] = {0.f, 0.f, 0.f, 0.f};
    #pragma unroll
    for (int mt = 0; mt < 4; ++mt)
        #pragma unroll
        for (int r = 0; r < 4; ++r) {
            int oc = wid * 64 + mt * 16 + quad * 4 + r;
            float bo = bl[oc];
            #pragma unroll
            for (int nt = 0; nt < 4; ++nt) {
                float v = acc[mt][nt][r] + bo;
                acc[mt][nt][r] = v;
                part[nt] += v * v;
            }
        }
    __syncthreads();
    #pragma unroll
    for (int nt = 0; nt < 4; ++nt)
        red[(nt * 16 + l15) * 17 + wid * 4 + quad] = part[nt];
    __syncthreads();
    if (tid < 64) {
        float s = 0.f;
        #pragma unroll
        for (int g = 0; g < 16; ++g) s += red[tid * 17 + g];
        invs[tid] = 1.0f / fmaxf(sqrtf(s), 1e-12f);
    }
    __syncthreads();
    #pragma unroll
    for (int mt = 0; mt < 4; ++mt)
        #pragma unroll
        for (int nt = 0; nt < 4; ++nt) {
            int pix = nt * 16 + l15;
            float iv = invs[pix];
            #pragma unroll
            for (int r = 0; r < 4; ++r) {
                int oc = wid * 64 + mt * 16 + quad * 4 + r;
                y[((size_t)(b * CC + oc)) * HW + hwb + pix] = acc[mt][nt][r] * iv * gl[oc] * 16.0f;
            }
        }
}

extern "C" void kernel_launch(void* const* d_in, const int* in_sizes, int n_in,
                              void* d_out, int out_size, void* d_ws, size_t ws_size,
                              hipStream_t stream) {
    const float* x     = (const float*)d_in[0];
    const float* g1    = (const float*)d_in[1];
    const float* memkv = (const float*)d_in[2];
    const float* wqkv  = (const float*)d_in[3];
    const float* wout  = (const float*)d_in[4];
    const float* bout  = (const float*)d_in[5];
    const float* g2    = (const float*)d_in[6];
    float* y = (float*)d_out;

    char* w = (char*)d_ws;
    ushort* wq2t  = (ushort*)w;  w += (size_t)OC3 * CC * 2;
    ushort* woutt = (ushort*)w;  w += (size_t)CC * HID * 2;
    float*  kmaxb = (float*)w;   w += 4096 * 4;
    float*  rsumb = (float*)w;   w += 4096 * 4;
    float*  ctxp  = (float*)w;   w += (size_t)NPART * 131072 * 4;  // 4 MB
    ushort* W2    = (ushort*)w;  w += (size_t)32 * CC * HID * 2;   // 2 MB
    ushort* xnT   = (ushort*)w;  w += (size_t)32 * HW * CC * 2;    // 67 MB
    ushort* qkv   = (ushort*)w;  w += (size_t)32 * OC3 * HW * 2;   // 100 MB (q third unused)

    k_xn    <<<dim3(4096),      dim3(256), 0, stream>>>(x, wqkv, g1, wout, wq2t, woutt, xnT);
    k_qkv   <<<dim3(2, 32, 32), dim3(256), 0, stream>>>(wq2t, xnT, qkv);
    k_ksoft <<<dim3(1024),      dim3(256), 0, stream>>>(qkv, memkv, kmaxb, rsumb);
    k_ctx   <<<dim3(128, 8),    dim3(256), 0, stream>>>(qkv, memkv, kmaxb, rsumb, ctxp);
    k_w2    <<<dim3(32),        dim3(256), 0, stream>>>(ctxp, woutt, W2);
    k_final <<<dim3(64, 32),    dim3(256), 0, stream>>>(xnT, wq2t, W2, bout, g2, y);
}

// Round 11
// 343.958 us; speedup vs baseline: 1.2282x; 1.0275x over previous
//
#include <hip/hip_runtime.h>
#include <math.h>

#define CC   256
#define HW   4096
#define OC3  384
#define HID  128
#define DH   32
#define NM   4
#define NPART 8
#define SCALE 0.17677669529663688f  // 32^-0.5

typedef __bf16 bf16x8 __attribute__((ext_vector_type(8)));
typedef float  f32x4  __attribute__((ext_vector_type(4)));

__device__ __forceinline__ ushort f2bf(float x) {
    union { float f; unsigned u; } v; v.f = x;
    unsigned r = v.u + 0x7fffu + ((v.u >> 16) & 1u);   // RNE
    return (ushort)(r >> 16);
}
__device__ __forceinline__ float bf2f(ushort b) {
    union { unsigned u; float f; } v; v.u = ((unsigned)b) << 16; return v.f;
}
__device__ __forceinline__ void g2l16(const void* g, void* l) {
    __builtin_amdgcn_global_load_lds(
        (const __attribute__((address_space(1))) void*)g,
        (__attribute__((address_space(3))) void*)l, 16, 0, 0);
}

// ---------------- fused rms-norm + transpose + bf16: xnT[b][pix][c]
// float4 global loads; LDS stride 36. k_prep merged (blocks 0..383).
__global__ __launch_bounds__(256) void k_xn(const float* __restrict__ x,
        const float* __restrict__ wqkv, const float* __restrict__ g1,
        const float* __restrict__ wout,
        ushort* __restrict__ wq2t, ushort* __restrict__ woutt,
        ushort* __restrict__ xnT) {
    __shared__ float xt[256 * 36];
    __shared__ float ps[8 * 33];
    __shared__ float invn[32];
    int tid = threadIdx.x;
    if (blockIdx.x < 384) {           // merged k_prep
        int o = blockIdx.x;
        wq2t[(size_t)o * CC + tid] = f2bf(wqkv[(size_t)o * CC + tid] * g1[tid] * 16.0f);
        if (o < CC && tid < HID) woutt[(size_t)o * HID + tid] = f2bf(wout[(size_t)o * HID + tid]);
    }
    int pix0 = blockIdx.x * 32;
    int b = pix0 >> 12, hw0 = pix0 & 4095;
    int p = tid & 31, cg = tid >> 5;
    const float* xb = x + (size_t)b * CC * HW + hw0;
    {
        int cr = tid >> 3;
        int chunk = tid & 7;
        #pragma unroll
        for (int pass = 0; pass < 8; ++pass) {
            int c = pass * 32 + cr;
            float4 v = *(const float4*)&xb[(size_t)c * HW + chunk * 4];
            *(float4*)&xt[c * 36 + chunk * 4] = v;
        }
    }
    __syncthreads();
    float s = 0.f;
    #pragma unroll 8
    for (int i = 0; i < 32; ++i) { float v = xt[(cg * 32 + i) * 36 + p]; s += v * v; }
    ps[cg * 33 + p] = s;
    __syncthreads();
    if (tid < 32) {
        float t = 0.f;
        #pragma unroll
        for (int g = 0; g < 8; ++g) t += ps[g * 33 + tid];
        invn[tid] = 1.0f / fmaxf(sqrtf(t), 1e-12f);
    }
    __syncthreads();
    float inv = invn[p];
    ushort* dst = xnT + ((size_t)(pix0 + p)) * CC + cg * 32;
    #pragma unroll
    for (int q = 0; q < 4; ++q) {
        uint4 pk; ushort* o8 = (ushort*)&pk;
        #pragma unroll
        for (int i = 0; i < 8; ++i) o8[i] = f2bf(xt[(cg * 32 + q * 8 + i) * 36 + p] * inv);
        *(uint4*)&dst[q * 8] = pk;
    }
}

// ---------------- k/v MFMA GEMM (q computed in k_final). Grid 2x32x32.
__global__ __launch_bounds__(256) void k_qkv(const ushort* __restrict__ wq2t,
        const ushort* __restrict__ xnT, ushort* __restrict__ qkv) {
    __shared__ __align__(16) ushort As[2][128 * 32];
    __shared__ __align__(16) ushort Bs[2][128 * 32];
    int tid = threadIdx.x;
    int lin = blockIdx.x + 2 * (blockIdx.y + 32 * blockIdx.z);   // 0..2047
    int swz = (lin & 7) * 256 + (lin >> 3);                      // XCD-bijective
    int m0 = 128 + (swz % 2) * 128;                              // k or v rows
    int t_ = swz / 2;
    int p0 = (t_ & 31) * 128;
    int b  = t_ >> 5;
    int lane = tid & 63, wid = tid >> 6;
    int l15 = tid & 15, quad = (tid >> 4) & 3;
    int wm = wid >> 1, wn = wid & 1;
    int rsub = lane >> 2;
    const ushort* Ab = wq2t + (size_t)m0 * CC;
    const ushort* Bb = xnT + ((size_t)(b * HW + p0)) * CC;
    f32x4 acc[4][4];
    #pragma unroll
    for (int i = 0; i < 4; ++i)
        #pragma unroll
        for (int j = 0; j < 4; ++j) acc[i][j] = (f32x4){0.f, 0.f, 0.f, 0.f};

    auto stage = [&](int buf, int k0) {
        #pragma unroll
        for (int q = 0; q < 2; ++q) {
            int rw = wid * 32 + q * 16;
            int r  = rw + rsub;
            int sc = (lane & 3) ^ ((r >> 1) & 3);
            g2l16(Ab + (size_t)r * CC + k0 + sc * 8, &As[buf][rw * 32]);
            g2l16(Bb + (size_t)r * CC + k0 + sc * 8, &Bs[buf][rw * 32]);
        }
    };

    stage(0, 0);
    __syncthreads();
    #pragma unroll
    for (int s = 0; s < 8; ++s) {
        int cur = s & 1;
        if (s < 7) stage(cur ^ 1, (s + 1) * 32);
        bf16x8 af[4], bfr[4];
        #pragma unroll
        for (int mt = 0; mt < 4; ++mt) {
            int ra = wm * 64 + mt * 16 + l15;
            af[mt] = *(const bf16x8*)&As[cur][ra * 32 + ((quad ^ ((ra >> 1) & 3)) << 3)];
        }
        #pragma unroll
        for (int nt = 0; nt < 4; ++nt) {
            int rb = wn * 64 + nt * 16 + l15;
            bfr[nt] = *(const bf16x8*)&Bs[cur][rb * 32 + ((quad ^ ((rb >> 1) & 3)) << 3)];
        }
        #pragma unroll
        for (int mt = 0; mt < 4; ++mt)
            #pragma unroll
            for (int nt = 0; nt < 4; ++nt)
                acc[mt][nt] = __builtin_amdgcn_mfma_f32_16x16x32_bf16(
                                  af[mt], bfr[nt], acc[mt][nt], 0, 0, 0);
        __syncthreads();
    }
    #pragma unroll
    for (int mt = 0; mt < 4; ++mt) {
        int o = m0 + wm * 64 + mt * 16 + quad * 4;
        #pragma unroll
        for (int nt = 0; nt < 4; ++nt) {
            int pix = p0 + wn * 64 + nt * 16 + l15;
            ushort* dst = qkv + ((size_t)(b * OC3 + o)) * HW + pix;
            #pragma unroll
            for (int r = 0; r < 4; ++r) dst[(size_t)r * HW] = f2bf(acc[mt][nt][r]);
        }
    }
}

// ---------------- context partials, flash-style: per-part local softmax stats
// (k_ksoft DELETED). Stage exp(k - m_p) unscaled; emit raw ctx_p + (m_p, s_p).
// Merge (incl. mem-kv) happens in k_w2. k rows now read exactly once.
__global__ __launch_bounds__(256) void k_ctx(const ushort* __restrict__ qkv,
        float* __restrict__ ctxp, float* __restrict__ mstat, float* __restrict__ sstat) {
    __shared__ __align__(16) char smem[32768];
    ushort* klw = (ushort*)smem;             // [4 waves][32 d][64 n] bf16, swizzled
    ushort* vlw = (ushort*)(smem + 16384);
    float*  red = (float*)smem;              // aliases klw (dead after MFMA)
    __shared__ float mred[4][32];
    __shared__ float sred[4][32];
    int tid = threadIdx.x;
    int lane = tid & 63, wid = tid >> 6;
    int l15 = lane & 15, quad = lane >> 4;
    int bh = blockIdx.x, part = blockIdx.y;
    int b = bh >> 2, h = bh & 3;
    int r  = lane >> 1;                 // staged row 0..31 (2 lanes/row)
    int ch = (lane & 1) * 32;
    const ushort* kp = qkv + ((size_t)(b * OC3 + HID + h * DH) + r) * HW + part * 512;
    const ushort* vp = qkv + ((size_t)(b * OC3 + 2 * HID + h * DH) + r) * HW + part * 512;
    ushort* myk = klw + wid * 2048;
    ushort* myv = vlw + wid * 2048;

    // phase 1: preload k (regs), local row max -> cross-wave reduce
    uint4 kreg[2][4];
    float lm = -1e30f;
    #pragma unroll
    for (int t = 0; t < 2; ++t) {
        int n0 = wid * 64 + t * 256;
        #pragma unroll
        for (int i = 0; i < 4; ++i) {
            kreg[t][i] = *(const uint4*)&kp[n0 + ch + i * 8];
            const ushort* ke = (const ushort*)&kreg[t][i];
            #pragma unroll
            for (int j = 0; j < 8; ++j) lm = fmaxf(lm, bf2f(ke[j]));
        }
    }
    lm = fmaxf(lm, __shfl_xor(lm, 1));
    if ((lane & 1) == 0) mred[wid][r] = lm;
    __syncthreads();
    float mp = fmaxf(fmaxf(mred[0][r], mred[1][r]), fmaxf(mred[2][r], mred[3][r]));

    f32x4 acc[2][2];
    #pragma unroll
    for (int i = 0; i < 2; ++i)
        #pragma unroll
        for (int j = 0; j < 2; ++j) acc[i][j] = (f32x4){0.f, 0.f, 0.f, 0.f};
    float ls = 0.f;
    #pragma unroll
    for (int t = 0; t < 2; ++t) {
        int n0 = wid * 64 + t * 256;
        #pragma unroll
        for (int i = 0; i < 4; ++i) {
            uint4 vv4 = *(const uint4*)&vp[n0 + ch + i * 8];
            uint4 ko; ushort* kw = (ushort*)&ko; const ushort* ke = (const ushort*)&kreg[t][i];
            #pragma unroll
            for (int j = 0; j < 8; ++j) {
                float e = __expf(bf2f(ke[j]) - mp);
                ls += e;
                kw[j] = f2bf(e);
            }
            int boff = ((ch + i * 8) * 2) ^ ((r & 7) << 4);
            *(uint4*)((char*)&myk[r * 64] + boff) = ko;
            *(uint4*)((char*)&myv[r * 64] + boff) = vv4;
        }
        #pragma unroll
        for (int ks = 0; ks < 2; ++ks) {
            bf16x8 af[2], bf[2];
            #pragma unroll
            for (int dt = 0; dt < 2; ++dt) {
                int row = dt * 16 + l15;
                int boff = (ks * 64 + quad * 16) ^ ((row & 7) << 4);
                af[dt] = *(const bf16x8*)((char*)&myk[row * 64] + boff);
                bf[dt] = *(const bf16x8*)((char*)&myv[row * 64] + boff);
            }
            #pragma unroll
            for (int dt = 0; dt < 2; ++dt)
                #pragma unroll
                for (int et = 0; et < 2; ++et)
                    acc[dt][et] = __builtin_amdgcn_mfma_f32_16x16x32_bf16(
                                      af[dt], bf[et], acc[dt][et], 0, 0, 0);
        }
    }
    ls += __shfl_xor(ls, 1);
    if ((lane & 1) == 0) sred[wid][r] = ls;
    __syncthreads();   // klw/vlw reads done (red alias safe) + sred complete
    if (tid < 32) {
        float s = sred[0][tid] + sred[1][tid] + sred[2][tid] + sred[3][tid];
        float m2 = fmaxf(fmaxf(mred[0][tid], mred[1][tid]),
                         fmaxf(mred[2][tid], mred[3][tid]));
        size_t o = ((size_t)part * 128 + bh) * 32 + tid;
        mstat[o] = m2;
        sstat[o] = s;
    }
    #pragma unroll
    for (int dt = 0; dt < 2; ++dt)
        #pragma unroll
        for (int et = 0; et < 2; ++et)
            #pragma unroll
            for (int rr = 0; rr < 4; ++rr) {
                int d = dt * 16 + quad * 4 + rr;
                int e = et * 16 + l15;
                red[wid * 1024 + d * 32 + e] = acc[dt][et][rr];
            }
    __syncthreads();
    {
        int o0 = tid * 4;
        f32x4 s4 = (f32x4){0.f, 0.f, 0.f, 0.f};
        #pragma unroll
        for (int w = 0; w < 4; ++w) {
            f32x4 v = *(const f32x4*)&red[w * 1024 + o0];
            s4[0] += v[0]; s4[1] += v[1]; s4[2] += v[2]; s4[3] += v[3];
        }
        *(f32x4*)&ctxp[(size_t)part * 131072 + (size_t)bh * 1024 + o0] = s4;
    }
}

// ---------------- merge flash stats + fold ctx into out-proj weight, per batch:
// row (h,d): M = max(m_p, mem-k); Z = sum s_p e^{m_p-M} + sum e^{mk-M};
// ctx[d][e] = (sum ctx_p e^{m_p-M} + sum e^{mk-M} vmem) / Z. Then W2 = wout @ ctx.
__global__ __launch_bounds__(256) void k_w2(const float* __restrict__ ctxp,
        const float* __restrict__ mstat, const float* __restrict__ sstat,
        const float* __restrict__ memkv,
        const ushort* __restrict__ woutt, ushort* __restrict__ W2) {
    __shared__ ushort ctxb[4 * 32 * 40];
    __shared__ float scl[NPART][128];
    __shared__ float memsc[128][NM];
    int tid = threadIdx.x, b = blockIdx.x;
    int wid = tid >> 6;
    int l15 = tid & 15, quad = (tid >> 4) & 3;
    if (tid < 128) {
        int h = tid >> 5, d = tid & 31;
        size_t base = (size_t)(b * 4 + h) * 32 + d;
        float mp[NPART];
        float M = -1e30f;
        #pragma unroll
        for (int p = 0; p < NPART; ++p) { mp[p] = mstat[(size_t)p * 4096 + base]; M = fmaxf(M, mp[p]); }
        float mk[NM];
        #pragma unroll
        for (int m = 0; m < NM; ++m) { mk[m] = memkv[(h * DH + d) * NM + m]; M = fmaxf(M, mk[m]); }
        float Z = 0.f;
        #pragma unroll
        for (int p = 0; p < NPART; ++p) Z += sstat[(size_t)p * 4096 + base] * __expf(mp[p] - M);
        #pragma unroll
        for (int m = 0; m < NM; ++m) Z += __expf(mk[m] - M);
        float iz = 1.0f / Z;
        #pragma unroll
        for (int p = 0; p < NPART; ++p) scl[p][tid] = __expf(mp[p] - M) * iz;
        #pragma unroll
        for (int m = 0; m < NM; ++m) memsc[tid][m] = __expf(mk[m] - M) * iz;
    }
    __syncthreads();
    #pragma unroll
    for (int j = 0; j < 16; ++j) {
        int idx = tid + j * 256;            // h*1024 + d*32 + e
        int rr = idx >> 5;                  // h*32 + d
        int e  = idx & 31;
        int h  = idx >> 10, d = (idx >> 5) & 31;
        float s = 0.f;
        #pragma unroll
        for (int p = 0; p < NPART; ++p)
            s += ctxp[(size_t)p * 131072 + (size_t)b * 4096 + idx] * scl[p][rr];
        #pragma unroll
        for (int m = 0; m < NM; ++m)
            s += memsc[rr][m] * memkv[512 + (h * DH + e) * NM + m];
        ctxb[(h * 32 + d) * 40 + e] = f2bf(s);
    }
    __syncthreads();
    #pragma unroll
    for (int h = 0; h < 4; ++h) {
        f32x4 acc[4][2];
        #pragma unroll
        for (int i = 0; i < 4; ++i)
            #pragma unroll
            for (int j = 0; j < 2; ++j) acc[i][j] = (f32x4){0.f, 0.f, 0.f, 0.f};
        bf16x8 af[4], bfr[2];
        #pragma unroll
        for (int mt = 0; mt < 4; ++mt)
            af[mt] = *(const bf16x8*)&woutt[(size_t)(wid * 64 + mt * 16 + l15) * HID
                                            + h * DH + quad * 8];
        #pragma unroll
        for (int nt = 0; nt < 2; ++nt)
            bfr[nt] = *(const bf16x8*)&ctxb[(h * 32 + nt * 16 + l15) * 40 + quad * 8];
        #pragma unroll
        for (int mt = 0; mt < 4; ++mt)
            #pragma unroll
            for (int nt = 0; nt < 2; ++nt)
                acc[mt][nt] = __builtin_amdgcn_mfma_f32_16x16x32_bf16(
                                  af[mt], bfr[nt], acc[mt][nt], 0, 0, 0);
        #pragma unroll
        for (int mt = 0; mt < 4; ++mt)
            #pragma unroll
            for (int nt = 0; nt < 2; ++nt)
                #pragma unroll
                for (int r = 0; r < 4; ++r) {
                    int oc = wid * 64 + mt * 16 + quad * 4 + r;
                    int d  = nt * 16 + l15;
                    W2[((size_t)b * CC + oc) * HID + h * DH + d] = f2bf(acc[mt][nt][r]);
                }
    }
}

// ---------------- final: q computed in-block (Wq @ xnT tile) -> softmax on fp32
// accs -> W2 GEMM -> bias + rms*g2. (R10 structure.)
__global__ __launch_bounds__(256) void k_final(const ushort* __restrict__ xnT,
        const ushort* __restrict__ wq2t, const ushort* __restrict__ W2,
        const float* __restrict__ bout, const float* __restrict__ g2,
        float* __restrict__ y) {
    __shared__ __align__(16) char smem[52224];
    ushort* xnTs = (ushort*)smem;              // [64][128]
    float*  red  = (float*)smem;               // aliases xnTs
    float*  invs = (float*)(smem + 4352);
    ushort* Qw   = (ushort*)(smem + 16384);    // [2][128*32]; aliased as WsQ
    ushort* sq   = (ushort*)(smem + 32768);    // [64][136]
    float*  bl   = (float*)(smem + 50176);
    float*  gl   = (float*)(smem + 51200);
    int tid = threadIdx.x;
    int b = blockIdx.y;
    int hwb = blockIdx.x * 64;
    int lane = tid & 63, wid = tid >> 6;
    int l15 = tid & 15, quad = (tid >> 4) & 3;
    int rsub = lane >> 2;
    bl[tid] = bout[tid];
    gl[tid] = g2[tid];

    auto stageX = [&](int half) {
        const ushort* xb = xnT + ((size_t)(b * HW + hwb)) * CC + half * 128;
        #pragma unroll
        for (int qq = 0; qq < 4; ++qq) {
            int r0 = qq * 16 + wid * 4;
            int r  = r0 + (lane >> 4);
            int g  = (lane & 15) ^ (r & 7);
            g2l16(xb + (size_t)r * CC + g * 8, &xnTs[r0 * 128]);
        }
    };
    auto stageQ = [&](int buf, int k0) {
        #pragma unroll
        for (int qq = 0; qq < 2; ++qq) {
            int rw = wid * 32 + qq * 16;
            int r  = rw + rsub;
            int sc = (lane & 3) ^ ((r >> 1) & 3);
            g2l16(wq2t + (size_t)r * CC + k0 + sc * 8, &Qw[buf * 4096 + rw * 32]);
        }
    };

    f32x4 accq[2][4];
    #pragma unroll
    for (int i = 0; i < 2; ++i)
        #pragma unroll
        for (int j = 0; j < 4; ++j) accq[i][j] = (f32x4){0.f, 0.f, 0.f, 0.f};
    stageX(0);
    stageQ(0, 0);
    __syncthreads();
    #pragma unroll
    for (int s = 0; s < 8; ++s) {
        int cur = s & 1;
        if (s < 7 && s != 3) stageQ(cur ^ 1, (s + 1) * 32);
        bf16x8 af[2], bfr[4];
        #pragma unroll
        for (int mt = 0; mt < 2; ++mt) {
            int ra = wid * 32 + mt * 16 + l15;
            af[mt] = *(const bf16x8*)&Qw[cur * 4096 + ra * 32 + ((quad ^ ((ra >> 1) & 3)) << 3)];
        }
        int cread = (s & 3) * 4 + quad;
        #pragma unroll
        for (int nt = 0; nt < 4; ++nt) {
            int rb = nt * 16 + l15;
            bfr[nt] = *(const bf16x8*)&xnTs[rb * 128 + ((cread ^ (rb & 7)) << 3)];
        }
        #pragma unroll
        for (int mt = 0; mt < 2; ++mt)
            #pragma unroll
            for (int nt = 0; nt < 4; ++nt)
                accq[mt][nt] = __builtin_amdgcn_mfma_f32_16x16x32_bf16(
                                   af[mt], bfr[nt], accq[mt][nt], 0, 0, 0);
        if (s == 3) {
            __syncthreads();
            stageX(1);
            stageQ(cur ^ 1, 128);
        }
        __syncthreads();
    }

    #pragma unroll
    for (int nt = 0; nt < 4; ++nt) {
        float m = -1e30f;
        #pragma unroll
        for (int mt = 0; mt < 2; ++mt)
            #pragma unroll
            for (int r = 0; r < 4; ++r) m = fmaxf(m, accq[mt][nt][r]);
        m = fmaxf(m, __shfl_xor(m, 16));
        m = fmaxf(m, __shfl_xor(m, 32));
        float s = 0.f;
        float e[2][4];
        #pragma unroll
        for (int mt = 0; mt < 2; ++mt)
            #pragma unroll
            for (int r = 0; r < 4; ++r) { e[mt][r] = __expf(accq[mt][nt][r] - m); s += e[mt][r]; }
        s += __shfl_xor(s, 16);
        s += __shfl_xor(s, 32);
        float r_ = SCALE / s;
        int pix = nt * 16 + l15;
        #pragma unroll
        for (int mt = 0; mt < 2; ++mt)
            #pragma unroll
            for (int r = 0; r < 4; ++r)
                sq[pix * 136 + wid * 32 + mt * 16 + quad * 4 + r] = f2bf(e[mt][r] * r_);
    }

    ushort* WsQ = Qw;
    f32x4 acc[4][4];
    #pragma unroll
    for (int i = 0; i < 4; ++i)
        #pragma unroll
        for (int j = 0; j < 4; ++j) acc[i][j] = (f32x4){0.f, 0.f, 0.f, 0.f};
    const ushort* W2b = W2 + (size_t)b * CC * HID;
    for (int k0 = 0; k0 < HID; k0 += 32) {
        __syncthreads();
        #pragma unroll
        for (int q = 0; q < 4; ++q) {
            int rw = wid * 64 + q * 16;
            int r  = rw + rsub;
            int sc = (lane & 3) ^ ((r >> 1) & 3);
            g2l16(W2b + (size_t)r * HID + k0 + sc * 8, &WsQ[rw * 32]);
        }
        __syncthreads();
        bf16x8 af[4], bfr[4];
        #pragma unroll
        for (int mt = 0; mt < 4; ++mt) {
            int ra = wid * 64 + mt * 16 + l15;
            af[mt] = *(const bf16x8*)&WsQ[ra * 32 + ((quad ^ ((ra >> 1) & 3)) << 3)];
        }
        #pragma unroll
        for (int nt = 0; nt < 4; ++nt)
            bfr[nt] = *(const bf16x8*)&sq[(nt * 16 + l15) * 136 + k0 + quad * 8];
        #pragma unroll
        for (int mt = 0; mt < 4; ++mt)
            #pragma unroll
            for (int nt = 0; nt < 4; ++nt)
                acc[mt][nt] = __builtin_amdgcn_mfma_f32_16x16x32_bf16(
                                  af[mt], bfr[nt], acc[mt][nt], 0, 0, 0);
    }

    float part[4] = {0.f, 0.f, 0.f, 0.f};
    #pragma unroll
    for (int mt = 0; mt < 4; ++mt)
        #pragma unroll
        for (int r = 0; r < 4; ++r) {
            int oc = wid * 64 + mt * 16 + quad * 4 + r;
            float bo = bl[oc];
            #pragma unroll
            for (int nt = 0; nt < 4; ++nt) {
                float v = acc[mt][nt][r] + bo;
                acc[mt][nt][r] = v;
                part[nt] += v * v;
            }
        }
    __syncthreads();
    #pragma unroll
    for (int nt = 0; nt < 4; ++nt)
        red[(nt * 16 + l15) * 17 + wid * 4 + quad] = part[nt];
    __syncthreads();
    if (tid < 64) {
        float s = 0.f;
        #pragma unroll
        for (int g = 0; g < 16; ++g) s += red[tid * 17 + g];
        invs[tid] = 1.0f / fmaxf(sqrtf(s), 1e-12f);
    }
    __syncthreads();
    #pragma unroll
    for (int mt = 0; mt < 4; ++mt)
        #pragma unroll
        for (int nt = 0; nt < 4; ++nt) {
            int pix = nt * 16 + l15;
            float iv = invs[pix];
            #pragma unroll
            for (int r = 0; r < 4; ++r) {
                int oc = wid * 64 + mt * 16 + quad * 4 + r;
                y[((size_t)(b * CC + oc)) * HW + hwb + pix] = acc[mt][nt][r] * iv * gl[oc] * 16.0f;
            }
        }
}

extern "C" void kernel_launch(void* const* d_in, const int* in_sizes, int n_in,
                              void* d_out, int out_size, void* d_ws, size_t ws_size,
                              hipStream_t stream) {
    const float* x     = (const float*)d_in[0];
    const float* g1    = (const float*)d_in[1];
    const float* memkv = (const float*)d_in[2];
    const float* wqkv  = (const float*)d_in[3];
    const float* wout  = (const float*)d_in[4];
    const float* bout  = (const float*)d_in[5];
    const float* g2    = (const float*)d_in[6];
    float* y = (float*)d_out;

    char* w = (char*)d_ws;
    ushort* wq2t  = (ushort*)w;  w += (size_t)OC3 * CC * 2;
    ushort* woutt = (ushort*)w;  w += (size_t)CC * HID * 2;
    float*  mstat = (float*)w;   w += (size_t)NPART * 4096 * 4;   // 128 KB
    float*  sstat = (float*)w;   w += (size_t)NPART * 4096 * 4;   // 128 KB
    float*  ctxp  = (float*)w;   w += (size_t)NPART * 131072 * 4; // 4 MB
    ushort* W2    = (ushort*)w;  w += (size_t)32 * CC * HID * 2;  // 2 MB
    ushort* xnT   = (ushort*)w;  w += (size_t)32 * HW * CC * 2;   // 67 MB
    ushort* qkv   = (ushort*)w;  w += (size_t)32 * OC3 * HW * 2;  // 100 MB (q third unused)

    k_xn    <<<dim3(4096),      dim3(256), 0, stream>>>(x, wqkv, g1, wout, wq2t, woutt, xnT);
    k_qkv   <<<dim3(2, 32, 32), dim3(256), 0, stream>>>(wq2t, xnT, qkv);
    k_ctx   <<<dim3(128, 8),    dim3(256), 0, stream>>>(qkv, ctxp, mstat, sstat);
    k_w2    <<<dim3(32),        dim3(256), 0, stream>>>(ctxp, mstat, sstat, memkv, woutt, W2);
    k_final <<<dim3(64, 32),    dim3(256), 0, stream>>>(xnT, wq2t, W2, bout, g2, y);
}